// Round 1
// baseline (1486.516 us; speedup 1.0000x reference)
//
#include <hip/hip_runtime.h>
#include <cstddef>

#define B_ 4
#define NQ_ 512
#define N_ 256
#define D_ 768
#define H_ 6
#define DH_ 128
#define G_ 64
#define R_ 64
#define MID_ 4096
#define VREP_ 8
#define EPS_ 1e-5f
#define SCALE_ 0.29730177875068026f  // 128^-0.25

// ---------------- block reduce (256 threads) ----------------
__device__ __forceinline__ void block_reduce2(float& s, float& q2, float* reds, float* redq) {
#pragma unroll
  for (int off = 32; off; off >>= 1) {
    s  += __shfl_down(s, off);
    q2 += __shfl_down(q2, off);
  }
  int w = threadIdx.x >> 6;
  if ((threadIdx.x & 63) == 0) { reds[w] = s; redq[w] = q2; }
  __syncthreads();
  s  = reds[0] + reds[1] + reds[2] + reds[3];
  q2 = redq[0] + redq[1] + redq[2] + redq[3];
}

// ---------------- generic SGEMM: C = A(MxK) @ B(KxNc) ----------------
// tile 128x64, block 256 threads, thread tile 8x4
__global__ __launch_bounds__(256) void sgemm_kernel(
    const float* __restrict__ A, const float* __restrict__ Bm,
    float* __restrict__ C, int M, int K, int Nc) {
  __shared__ __align__(16) float As[16][128];
  __shared__ __align__(16) float Bs[16][64];
  int t = threadIdx.x;
  int tx = t & 15, ty = t >> 4;
  int bm = blockIdx.y * 128, bn = blockIdx.x * 64;
  float4 acc[8];
#pragma unroll
  for (int i = 0; i < 8; ++i) acc[i] = make_float4(0.f, 0.f, 0.f, 0.f);

  int am = t >> 1, ak = (t & 1) * 8;
  int bk = t >> 4, bn4 = (t & 15) * 4;
  const float* Ap = A + (size_t)(bm + am) * K + ak;
  const float* Bp = Bm + (size_t)bk * Nc + bn + bn4;

  for (int k0 = 0; k0 < K; k0 += 16) {
    float4 a0 = *(const float4*)(Ap + k0);
    float4 a1 = *(const float4*)(Ap + k0 + 4);
    float4 b0 = *(const float4*)(Bp + (size_t)k0 * Nc);
    As[ak + 0][am] = a0.x; As[ak + 1][am] = a0.y; As[ak + 2][am] = a0.z; As[ak + 3][am] = a0.w;
    As[ak + 4][am] = a1.x; As[ak + 5][am] = a1.y; As[ak + 6][am] = a1.z; As[ak + 7][am] = a1.w;
    *(float4*)&Bs[bk][bn4] = b0;
    __syncthreads();
#pragma unroll
    for (int k = 0; k < 16; ++k) {
      float4 av0 = *(const float4*)&As[k][ty * 8];
      float4 av1 = *(const float4*)&As[k][ty * 8 + 4];
      float4 bv  = *(const float4*)&Bs[k][tx * 4];
      float ar[8] = {av0.x, av0.y, av0.z, av0.w, av1.x, av1.y, av1.z, av1.w};
#pragma unroll
      for (int i = 0; i < 8; ++i) {
        acc[i].x += ar[i] * bv.x; acc[i].y += ar[i] * bv.y;
        acc[i].z += ar[i] * bv.z; acc[i].w += ar[i] * bv.w;
      }
    }
    __syncthreads();
  }
#pragma unroll
  for (int i = 0; i < 8; ++i)
    *(float4*)&C[(size_t)(bm + ty * 8 + i) * Nc + bn + tx * 4] = acc[i];
}

// ---------------- LayerNorm (row per block, optional scale, in-place safe) ----------------
__global__ __launch_bounds__(256) void ln_kernel(
    const float* in, float* outp,
    const float* __restrict__ gamma, const float* __restrict__ beta,
    int C, float scale) {
  __shared__ float reds[4], redq[4];
  int row = blockIdx.x;
  const float* xr = in + (size_t)row * C;
  float* orow = outp + (size_t)row * C;
  float s = 0.f, q2 = 0.f;
  for (int c = threadIdx.x; c < C; c += 256) {
    float v = xr[c]; s += v; q2 += v * v;
  }
  block_reduce2(s, q2, reds, redq);
  float mu = s / C;
  float var = q2 / C - mu * mu;
  float rstd = rsqrtf(var + EPS_);
  for (int c = threadIdx.x; c < C; c += 256)
    orow[c] = ((xr[c] - mu) * rstd * gamma[c] + beta[c]) * scale;
}

// ---------------- LN for k + transpose write: kT[b,h,d,j] ----------------
__global__ __launch_bounds__(256) void ln_k_kernel(
    const float* in, float* __restrict__ kT,
    const float* __restrict__ gamma, const float* __restrict__ beta) {
  __shared__ float reds[4], redq[4];
  int row = blockIdx.x;            // b*N + j
  int b = row >> 8, j = row & 255;
  const float* xr = in + (size_t)row * D_;
  float s = 0.f, q2 = 0.f;
  for (int c = threadIdx.x; c < D_; c += 256) {
    float v = xr[c]; s += v; q2 += v * v;
  }
  block_reduce2(s, q2, reds, redq);
  float mu = s / D_;
  float var = q2 / D_ - mu * mu;
  float rstd = rsqrtf(var + EPS_);
  for (int c = threadIdx.x; c < D_; c += 256) {
    float val = ((xr[c] - mu) * rstd * gamma[c] + beta[c]) * SCALE_;
    int h = c >> 7, dd = c & 127;
    kT[((size_t)((b * H_ + h) * DH_ + dd)) * N_ + j] = val;
  }
}

// ---------------- Wc prep: wcsum[g][r] = (1/D)sum_d Wc[g,d,r];
//                  Msum[g][r1][r2] = (1/D)sum_d Wc[g,d,r1]*Wc[g,d,r2] ----------------
__global__ __launch_bounds__(256) void wprep_kernel(
    const float* __restrict__ Wc, float* __restrict__ wcsum, float* __restrict__ Msum) {
  __shared__ __align__(16) float wd[16][64];
  int g = blockIdx.x, t = threadIdx.x;
  int r1 = t >> 2, r2b = (t & 3) * 16;
  float acc[16] = {};
  float wsum = 0.f;
  for (int d0 = 0; d0 < D_; d0 += 16) {
    for (int idx = t; idx < 1024; idx += 256)
      wd[idx >> 6][idx & 63] = Wc[((size_t)g * D_ + d0 + (idx >> 6)) * R_ + (idx & 63)];
    __syncthreads();
#pragma unroll 4
    for (int i = 0; i < 16; ++i) {
      float a = wd[i][r1];
#pragma unroll
      for (int kk = 0; kk < 16; ++kk) acc[kk] += a * wd[i][r2b + kk];
    }
    if (t < 64) {
#pragma unroll 4
      for (int i = 0; i < 16; ++i) wsum += wd[i][t];
    }
    __syncthreads();
  }
  const float inv = 1.f / (float)D_;
#pragma unroll
  for (int kk = 0; kk < 16; ++kk)
    Msum[(size_t)g * 4096 + r1 * 64 + r2b + kk] = acc[kk] * inv;
  if (t < 64) wcsum[g * 64 + t] = wsum * inv;
}

// ---------------- v stats without materializing v: quadratic form ----------------
__global__ __launch_bounds__(256) void vstats_kernel(
    const float* __restrict__ v1, const float* __restrict__ wcsum,
    const float* __restrict__ Msum, float* __restrict__ means, float* __restrict__ rstds) {
  __shared__ __align__(16) float Ms[4096];
  __shared__ float ws[64];
  int bg = blockIdx.x;
  int b = bg >> 6, g = bg & 63;
  int t = threadIdx.x;
  for (int idx = t; idx < 4096; idx += 256) Ms[idx] = Msum[(size_t)g * 4096 + idx];
  if (t < 64) ws[t] = wcsum[g * 64 + t];
  __syncthreads();
  const float* vp = v1 + ((size_t)(b * N_ + t)) * MID_ + g * R_;
  float v[64];
#pragma unroll
  for (int r4 = 0; r4 < 16; ++r4) {
    float4 x4 = *(const float4*)(vp + r4 * 4);
    v[r4 * 4 + 0] = x4.x; v[r4 * 4 + 1] = x4.y; v[r4 * 4 + 2] = x4.z; v[r4 * 4 + 3] = x4.w;
  }
  float mu = 0.f;
#pragma unroll
  for (int r = 0; r < 64; ++r) mu += v[r] * ws[r];
  float msq = 0.f;
#pragma unroll
  for (int r1 = 0; r1 < 64; ++r1) {
    const float4* mrow = (const float4*)&Ms[r1 * 64];
    float ts = 0.f;
#pragma unroll
    for (int r2 = 0; r2 < 16; ++r2) {
      float4 m4 = mrow[r2];
      ts += m4.x * v[r2 * 4] + m4.y * v[r2 * 4 + 1] + m4.z * v[r2 * 4 + 2] + m4.w * v[r2 * 4 + 3];
    }
    msq += v[r1] * ts;
  }
  float var = msq - mu * mu;
  means[bg * N_ + t] = mu;
  rstds[bg * N_ + t] = rsqrtf(var + EPS_);
}

// ---------------- attention scores + softmax ----------------
// grid (NQ/8, H, B), 256 threads; thread j = t
__global__ __launch_bounds__(256) void attn_kernel(
    const float* __restrict__ q, const float* __restrict__ kT, float* __restrict__ attn) {
  __shared__ __align__(16) float qs[8][128];
  __shared__ float sims[8][256];
  int b = blockIdx.z, h = blockIdx.y, i0 = blockIdx.x * 8;
  int t = threadIdx.x;
  for (int idx = t; idx < 1024; idx += 256) {
    int rr = idx >> 7, d = idx & 127;
    qs[rr][d] = q[((size_t)(b * NQ_ + i0 + rr)) * D_ + h * DH_ + d];
  }
  __syncthreads();
  const float* kp = kT + ((size_t)(b * H_ + h) * DH_) * N_ + t;
  float sim[8] = {};
  for (int d4 = 0; d4 < 32; ++d4) {
    float kv0 = kp[(d4 * 4 + 0) * N_];
    float kv1 = kp[(d4 * 4 + 1) * N_];
    float kv2 = kp[(d4 * 4 + 2) * N_];
    float kv3 = kp[(d4 * 4 + 3) * N_];
#pragma unroll
    for (int r = 0; r < 8; ++r) {
      float4 qv = *(const float4*)&qs[r][d4 * 4];
      sim[r] += qv.x * kv0 + qv.y * kv1 + qv.z * kv2 + qv.w * kv3;
    }
  }
#pragma unroll
  for (int r = 0; r < 8; ++r) sims[r][t] = sim[r];
  __syncthreads();
  int w = t >> 6, lane = t & 63;
#pragma unroll
  for (int rr = 0; rr < 2; ++rr) {
    int r = w * 2 + rr;
    float v0 = sims[r][lane], v1v = sims[r][lane + 64];
    float v2 = sims[r][lane + 128], v3 = sims[r][lane + 192];
    float mx = fmaxf(fmaxf(v0, v1v), fmaxf(v2, v3));
#pragma unroll
    for (int off = 32; off; off >>= 1) mx = fmaxf(mx, __shfl_xor(mx, off));
    float e0 = expf(v0 - mx), e1 = expf(v1v - mx), e2 = expf(v2 - mx), e3 = expf(v3 - mx);
    float s = e0 + e1 + e2 + e3;
#pragma unroll
    for (int off = 32; off; off >>= 1) s += __shfl_xor(s, off);
    float inv = 1.f / s;
    float* ap = attn + ((size_t)((b * H_ + h) * NQ_ + i0 + r)) * N_;
    ap[lane] = e0 * inv; ap[lane + 64] = e1 * inv;
    ap[lane + 128] = e2 * inv; ap[lane + 192] = e3 * inv;
  }
}

// ---------------- fused conv + LN + PV: block per (b,g), 768 threads (thread = out col d) ----------------
__global__ __launch_bounds__(768) void pv_kernel(
    const float* __restrict__ v1, const float* __restrict__ Wc,
    const float* __restrict__ attn, const float* __restrict__ means,
    const float* __restrict__ rstds, const float* __restrict__ gv2,
    const float* __restrict__ bv2, float* __restrict__ aout) {
  constexpr int VST = 260;  // padded stride: conflict-tame writes, 16B-aligned b128 reads
  __shared__ __align__(16) float v1sT[64 * VST];      // 66.6 KB
  __shared__ __align__(16) float attn_s[48 * 256];    // 49.2 KB
  __shared__ __align__(16) float mean_s[256];
  __shared__ __align__(16) float rstd_s[256];
  int bg = blockIdx.x, b = bg >> 6, g = bg & 63;
  int t = threadIdx.x, h = t >> 7;

  for (int idx = t; idx < 16384; idx += 768) {
    int n = idx >> 6, r = idx & 63;
    v1sT[r * VST + n] = v1[((size_t)(b * N_ + n)) * MID_ + g * R_ + r];
  }
  for (int idx = t; idx < 12288; idx += 768) {
    int j = idx & 255, hr = idx >> 8;  // hr = h*8 + rr
    attn_s[idx] = attn[((size_t)((b * H_ + (hr >> 3)) * NQ_ + (hr & 7) * G_ + g)) * N_ + j];
  }
  if (t < 256) {
    mean_s[t] = means[bg * N_ + t];
    rstd_s[t] = rstds[bg * N_ + t];
  }
  float wc[64];
  const float* wp = Wc + ((size_t)(g * D_ + t)) * R_;
#pragma unroll
  for (int r4 = 0; r4 < 16; ++r4) {
    float4 w4 = *(const float4*)(wp + r4 * 4);
    wc[r4 * 4 + 0] = w4.x; wc[r4 * 4 + 1] = w4.y; wc[r4 * 4 + 2] = w4.z; wc[r4 * 4 + 3] = w4.w;
  }
  float gg = gv2[t], bb = bv2[t];
  __syncthreads();

  float acc[8] = {};
  for (int j0 = 0; j0 < 256; j0 += 4) {
    float vx = 0.f, vy = 0.f, vz = 0.f, vw = 0.f;
#pragma unroll
    for (int r = 0; r < 64; ++r) {
      float4 vv = *(const float4*)&v1sT[r * VST + j0];
      vx += wc[r] * vv.x; vy += wc[r] * vv.y; vz += wc[r] * vv.z; vw += wc[r] * vv.w;
    }
    float4 mu4 = *(const float4*)&mean_s[j0];
    float4 rs4 = *(const float4*)&rstd_s[j0];
    float l0 = (vx - mu4.x) * rs4.x * gg + bb;
    float l1 = (vy - mu4.y) * rs4.y * gg + bb;
    float l2 = (vz - mu4.z) * rs4.z * gg + bb;
    float l3 = (vw - mu4.w) * rs4.w * gg + bb;
    const float* as_base = attn_s + h * 8 * 256 + j0;
#pragma unroll
    for (int rr = 0; rr < 8; ++rr) {
      float4 a4 = *(const float4*)(as_base + rr * 256);
      acc[rr] += a4.x * l0 + a4.y * l1 + a4.z * l2 + a4.w * l3;
    }
  }
#pragma unroll
  for (int rr = 0; rr < 8; ++rr)
    aout[((size_t)(b * NQ_ + rr * G_ + g)) * D_ + t] = acc[rr];
}

// ---------------- launch ----------------
extern "C" void kernel_launch(void* const* d_in, const int* in_sizes, int n_in,
                              void* d_out, int out_size, void* d_ws, size_t ws_size,
                              hipStream_t stream) {
  const float* x       = (const float*)d_in[0];
  const float* context = (const float*)d_in[1];
  const float* Wq  = (const float*)d_in[2];
  const float* gq  = (const float*)d_in[3];
  const float* bq  = (const float*)d_in[4];
  const float* Wk  = (const float*)d_in[5];
  const float* gk  = (const float*)d_in[6];
  const float* bk  = (const float*)d_in[7];
  const float* Wv1 = (const float*)d_in[8];
  const float* gv1 = (const float*)d_in[9];
  const float* bv1 = (const float*)d_in[10];
  const float* Wc  = (const float*)d_in[11];
  const float* gv2 = (const float*)d_in[12];
  const float* bv2 = (const float*)d_in[13];
  const float* Wout = (const float*)d_in[14];
  float* out = (float*)d_out;

  float* p = (float*)d_ws;
  float* q     = p; p += (size_t)B_ * NQ_ * D_;        // 1572864
  float* kT    = p; p += (size_t)B_ * H_ * DH_ * N_;   // 786432
  float* v1    = p; p += (size_t)B_ * N_ * MID_;       // 4194304
  float* attn  = p; p += (size_t)B_ * H_ * NQ_ * N_;   // 3145728
  float* means = p; p += (size_t)B_ * G_ * N_;         // 65536
  float* rstds = p; p += (size_t)B_ * G_ * N_;         // 65536
  float* aout  = p; p += (size_t)B_ * NQ_ * D_;        // 1572864 (also k-tmp)
  float* wcsum = p; p += (size_t)G_ * R_;              // 4096
  float* Msum  = p; p += (size_t)G_ * R_ * R_;         // 262144

  dim3 blk(256);
  // q = LN(x @ Wq) * scale
  sgemm_kernel<<<dim3(12, 16), blk, 0, stream>>>(x, Wq, q, 2048, D_, D_);
  ln_kernel<<<2048, blk, 0, stream>>>(q, q, gq, bq, D_, SCALE_);
  // kT = transpose(LN(context @ Wk) * scale)
  sgemm_kernel<<<dim3(12, 8), blk, 0, stream>>>(context, Wk, aout, 1024, D_, D_);
  ln_k_kernel<<<1024, blk, 0, stream>>>(aout, kT, gk, bk);
  // v1 = LN(context @ Wv1)
  sgemm_kernel<<<dim3(64, 8), blk, 0, stream>>>(context, Wv1, v1, 1024, D_, MID_);
  ln_kernel<<<1024, blk, 0, stream>>>(v1, v1, gv1, bv1, MID_, 1.0f);
  // LN stats of v via quadratic form (no v materialization)
  wprep_kernel<<<G_, blk, 0, stream>>>(Wc, wcsum, Msum);
  vstats_kernel<<<B_ * G_, blk, 0, stream>>>(v1, wcsum, Msum, means, rstds);
  // attention scores + softmax
  attn_kernel<<<dim3(NQ_ / 8, H_, B_), blk, 0, stream>>>(q, kT, attn);
  // fused grouped-conv + LN + PV
  pv_kernel<<<B_ * G_, dim3(768), 0, stream>>>(v1, Wc, attn, means, rstds, gv2, bv2, aout);
  // final projection
  sgemm_kernel<<<dim3(12, 16), blk, 0, stream>>>(aout, Wout, out, 2048, D_, D_);
}

// Round 2
// 791.717 us; speedup vs baseline: 1.8776x; 1.8776x over previous
//
#include <hip/hip_runtime.h>
#include <cstddef>

#define B_ 4
#define NQ_ 512
#define N_ 256
#define D_ 768
#define H_ 6
#define DH_ 128
#define G_ 64
#define R_ 64
#define MID_ 4096
#define VREP_ 8
#define EPS_ 1e-5f
#define SCALE_ 0.29730177875068026f  // 128^-0.25

// ---------------- block reduce (256 threads) ----------------
__device__ __forceinline__ void block_reduce2(float& s, float& q2, float* reds, float* redq) {
#pragma unroll
  for (int off = 32; off; off >>= 1) {
    s  += __shfl_down(s, off);
    q2 += __shfl_down(q2, off);
  }
  int w = threadIdx.x >> 6;
  if ((threadIdx.x & 63) == 0) { reds[w] = s; redq[w] = q2; }
  __syncthreads();
  s  = reds[0] + reds[1] + reds[2] + reds[3];
  q2 = redq[0] + redq[1] + redq[2] + redq[3];
}

// ---------------- generic SGEMM: C = A(MxK) @ B(KxNc) ----------------
// tile 128x64, block 256 threads, thread tile 8x4
__global__ __launch_bounds__(256) void sgemm_kernel(
    const float* __restrict__ A, const float* __restrict__ Bm,
    float* __restrict__ C, int M, int K, int Nc) {
  __shared__ __align__(16) float As[16][128];
  __shared__ __align__(16) float Bs[16][64];
  int t = threadIdx.x;
  int tx = t & 15, ty = t >> 4;
  int bm = blockIdx.y * 128, bn = blockIdx.x * 64;
  float4 acc[8];
#pragma unroll
  for (int i = 0; i < 8; ++i) acc[i] = make_float4(0.f, 0.f, 0.f, 0.f);

  int am = t >> 1, ak = (t & 1) * 8;
  int bk = t >> 4, bn4 = (t & 15) * 4;
  const float* Ap = A + (size_t)(bm + am) * K + ak;
  const float* Bp = Bm + (size_t)bk * Nc + bn + bn4;

  for (int k0 = 0; k0 < K; k0 += 16) {
    float4 a0 = *(const float4*)(Ap + k0);
    float4 a1 = *(const float4*)(Ap + k0 + 4);
    float4 b0 = *(const float4*)(Bp + (size_t)k0 * Nc);
    As[ak + 0][am] = a0.x; As[ak + 1][am] = a0.y; As[ak + 2][am] = a0.z; As[ak + 3][am] = a0.w;
    As[ak + 4][am] = a1.x; As[ak + 5][am] = a1.y; As[ak + 6][am] = a1.z; As[ak + 7][am] = a1.w;
    *(float4*)&Bs[bk][bn4] = b0;
    __syncthreads();
#pragma unroll
    for (int k = 0; k < 16; ++k) {
      float4 av0 = *(const float4*)&As[k][ty * 8];
      float4 av1 = *(const float4*)&As[k][ty * 8 + 4];
      float4 bv  = *(const float4*)&Bs[k][tx * 4];
      float ar[8] = {av0.x, av0.y, av0.z, av0.w, av1.x, av1.y, av1.z, av1.w};
#pragma unroll
      for (int i = 0; i < 8; ++i) {
        acc[i].x += ar[i] * bv.x; acc[i].y += ar[i] * bv.y;
        acc[i].z += ar[i] * bv.z; acc[i].w += ar[i] * bv.w;
      }
    }
    __syncthreads();
  }
#pragma unroll
  for (int i = 0; i < 8; ++i)
    *(float4*)&C[(size_t)(bm + ty * 8 + i) * Nc + bn + tx * 4] = acc[i];
}

// ---------------- LayerNorm (row per block, optional scale, in-place safe) ----------------
__global__ __launch_bounds__(256) void ln_kernel(
    const float* in, float* outp,
    const float* __restrict__ gamma, const float* __restrict__ beta,
    int C, float scale) {
  __shared__ float reds[4], redq[4];
  int row = blockIdx.x;
  const float* xr = in + (size_t)row * C;
  float* orow = outp + (size_t)row * C;
  float s = 0.f, q2 = 0.f;
  for (int c = threadIdx.x; c < C; c += 256) {
    float v = xr[c]; s += v; q2 += v * v;
  }
  block_reduce2(s, q2, reds, redq);
  float mu = s / C;
  float var = q2 / C - mu * mu;
  float rstd = rsqrtf(var + EPS_);
  for (int c = threadIdx.x; c < C; c += 256)
    orow[c] = ((xr[c] - mu) * rstd * gamma[c] + beta[c]) * scale;
}

// ---------------- LN for k + transpose write: kT[b,h,d,j] ----------------
__global__ __launch_bounds__(256) void ln_k_kernel(
    const float* in, float* __restrict__ kT,
    const float* __restrict__ gamma, const float* __restrict__ beta) {
  __shared__ float reds[4], redq[4];
  int row = blockIdx.x;            // b*N + j
  int b = row >> 8, j = row & 255;
  const float* xr = in + (size_t)row * D_;
  float s = 0.f, q2 = 0.f;
  for (int c = threadIdx.x; c < D_; c += 256) {
    float v = xr[c]; s += v; q2 += v * v;
  }
  block_reduce2(s, q2, reds, redq);
  float mu = s / D_;
  float var = q2 / D_ - mu * mu;
  float rstd = rsqrtf(var + EPS_);
  for (int c = threadIdx.x; c < D_; c += 256) {
    float val = ((xr[c] - mu) * rstd * gamma[c] + beta[c]) * SCALE_;
    int h = c >> 7, dd = c & 127;
    kT[((size_t)((b * H_ + h) * DH_ + dd)) * N_ + j] = val;
  }
}

// ---------------- Wc prep: wcsum[g][r] = (1/D)sum_d Wc[g,d,r];
//                  Msum[g][r1][r2] = (1/D)sum_d Wc[g,d,r1]*Wc[g,d,r2] ----------------
__global__ __launch_bounds__(256) void wprep_kernel(
    const float* __restrict__ Wc, float* __restrict__ wcsum, float* __restrict__ Msum) {
  __shared__ __align__(16) float wd[16][64];
  int g = blockIdx.x, t = threadIdx.x;
  int r1 = t >> 2, r2b = (t & 3) * 16;
  float acc[16] = {};
  float wsum = 0.f;
  for (int d0 = 0; d0 < D_; d0 += 16) {
    for (int idx = t; idx < 1024; idx += 256)
      wd[idx >> 6][idx & 63] = Wc[((size_t)g * D_ + d0 + (idx >> 6)) * R_ + (idx & 63)];
    __syncthreads();
#pragma unroll 4
    for (int i = 0; i < 16; ++i) {
      float a = wd[i][r1];
#pragma unroll
      for (int kk = 0; kk < 16; ++kk) acc[kk] += a * wd[i][r2b + kk];
    }
    if (t < 64) {
#pragma unroll 4
      for (int i = 0; i < 16; ++i) wsum += wd[i][t];
    }
    __syncthreads();
  }
  const float inv = 1.f / (float)D_;
#pragma unroll
  for (int kk = 0; kk < 16; ++kk)
    Msum[(size_t)g * 4096 + r1 * 64 + r2b + kk] = acc[kk] * inv;
  if (t < 64) wcsum[g * 64 + t] = wsum * inv;
}

// ---------------- v stats without materializing v: quadratic form ----------------
__global__ __launch_bounds__(256) void vstats_kernel(
    const float* __restrict__ v1, const float* __restrict__ wcsum,
    const float* __restrict__ Msum, float* __restrict__ means, float* __restrict__ rstds) {
  __shared__ __align__(16) float Ms[4096];
  __shared__ float ws[64];
  int bg = blockIdx.x;
  int b = bg >> 6, g = bg & 63;
  int t = threadIdx.x;
  for (int idx = t; idx < 4096; idx += 256) Ms[idx] = Msum[(size_t)g * 4096 + idx];
  if (t < 64) ws[t] = wcsum[g * 64 + t];
  __syncthreads();
  const float* vp = v1 + ((size_t)(b * N_ + t)) * MID_ + g * R_;
  float v[64];
#pragma unroll
  for (int r4 = 0; r4 < 16; ++r4) {
    float4 x4 = *(const float4*)(vp + r4 * 4);
    v[r4 * 4 + 0] = x4.x; v[r4 * 4 + 1] = x4.y; v[r4 * 4 + 2] = x4.z; v[r4 * 4 + 3] = x4.w;
  }
  float mu = 0.f;
#pragma unroll
  for (int r = 0; r < 64; ++r) mu += v[r] * ws[r];
  float msq = 0.f;
#pragma unroll
  for (int r1 = 0; r1 < 64; ++r1) {
    const float4* mrow = (const float4*)&Ms[r1 * 64];
    float ts = 0.f;
#pragma unroll
    for (int r2 = 0; r2 < 16; ++r2) {
      float4 m4 = mrow[r2];
      ts += m4.x * v[r2 * 4] + m4.y * v[r2 * 4 + 1] + m4.z * v[r2 * 4 + 2] + m4.w * v[r2 * 4 + 3];
    }
    msq += v[r1] * ts;
  }
  float var = msq - mu * mu;
  means[bg * N_ + t] = mu;
  rstds[bg * N_ + t] = rsqrtf(var + EPS_);
}

// ---------------- attention scores + softmax ----------------
// grid (NQ/8, H, B), 256 threads; thread j = t
__global__ __launch_bounds__(256) void attn_kernel(
    const float* __restrict__ q, const float* __restrict__ kT, float* __restrict__ attn) {
  __shared__ __align__(16) float qs[8][128];
  __shared__ float sims[8][256];
  int b = blockIdx.z, h = blockIdx.y, i0 = blockIdx.x * 8;
  int t = threadIdx.x;
  for (int idx = t; idx < 1024; idx += 256) {
    int rr = idx >> 7, d = idx & 127;
    qs[rr][d] = q[((size_t)(b * NQ_ + i0 + rr)) * D_ + h * DH_ + d];
  }
  __syncthreads();
  const float* kp = kT + ((size_t)(b * H_ + h) * DH_) * N_ + t;
  float sim[8] = {};
  for (int d4 = 0; d4 < 32; ++d4) {
    float kv0 = kp[(d4 * 4 + 0) * N_];
    float kv1 = kp[(d4 * 4 + 1) * N_];
    float kv2 = kp[(d4 * 4 + 2) * N_];
    float kv3 = kp[(d4 * 4 + 3) * N_];
#pragma unroll
    for (int r = 0; r < 8; ++r) {
      float4 qv = *(const float4*)&qs[r][d4 * 4];
      sim[r] += qv.x * kv0 + qv.y * kv1 + qv.z * kv2 + qv.w * kv3;
    }
  }
#pragma unroll
  for (int r = 0; r < 8; ++r) sims[r][t] = sim[r];
  __syncthreads();
  int w = t >> 6, lane = t & 63;
#pragma unroll
  for (int rr = 0; rr < 2; ++rr) {
    int r = w * 2 + rr;
    float v0 = sims[r][lane], v1v = sims[r][lane + 64];
    float v2 = sims[r][lane + 128], v3 = sims[r][lane + 192];
    float mx = fmaxf(fmaxf(v0, v1v), fmaxf(v2, v3));
#pragma unroll
    for (int off = 32; off; off >>= 1) mx = fmaxf(mx, __shfl_xor(mx, off));
    float e0 = expf(v0 - mx), e1 = expf(v1v - mx), e2 = expf(v2 - mx), e3 = expf(v3 - mx);
    float s = e0 + e1 + e2 + e3;
#pragma unroll
    for (int off = 32; off; off >>= 1) s += __shfl_xor(s, off);
    float inv = 1.f / s;
    float* ap = attn + ((size_t)((b * H_ + h) * NQ_ + i0 + r)) * N_;
    ap[lane] = e0 * inv; ap[lane + 64] = e1 * inv;
    ap[lane + 128] = e2 * inv; ap[lane + 192] = e3 * inv;
  }
}

// ---------------- fused conv + LN + PV: block per (b,g), 768 threads (thread = out col d)
// LDS layout chosen so ALL main-loop reads are wave-uniform broadcasts (conflict-free):
//   v1s[n][r]      (n-major, contiguous staging writes)
//   attn_s[h][n][rr] (2x b128 broadcast per n)
// __launch_bounds__(768,3): 3 waves/EU -> ~170 VGPR cap so wc[64] stays in registers
// (round-1 spill of wc[64] to scratch caused 2.08 GB HBM fetch / 27x overfetch). ----------------
__global__ __launch_bounds__(768, 3) void pv_kernel(
    const float* __restrict__ v1, const float* __restrict__ Wc,
    const float* __restrict__ attn, const float* __restrict__ means,
    const float* __restrict__ rstds, const float* __restrict__ gv2,
    const float* __restrict__ bv2, float* __restrict__ aout) {
  __shared__ __align__(16) float v1s[N_ * R_];          // 64 KB, [n][r]
  __shared__ __align__(16) float attn_s[H_ * N_ * 8];   // 48 KB, [h][n][rr]
  __shared__ __align__(16) float mean_s[N_];
  __shared__ __align__(16) float rstd_s[N_];
  int bg = blockIdx.x, b = bg >> 6, g = bg & 63;
  int t = threadIdx.x, h = t >> 7;

  // stage v1 slice: global read 256B-coalesced, LDS write fully contiguous
  for (int idx = t; idx < N_ * R_; idx += 768) {
    v1s[idx] = v1[((size_t)(b * N_ + (idx >> 6))) * MID_ + g * R_ + (idx & 63)];
  }
  // stage attn rows i = rr*G+g for all h, transposed to [h][j][rr]
  for (int idx = t; idx < 12288; idx += 768) {
    int j = idx & 255, hr = idx >> 8;  // hr = hh*8 + rr
    int hh = hr >> 3, rr = hr & 7;
    attn_s[(hh * 256 + j) * 8 + rr] =
        attn[((size_t)((b * H_ + hh) * NQ_ + rr * G_ + g)) * N_ + j];
  }
  if (t < 256) {
    mean_s[t] = means[bg * N_ + t];
    rstd_s[t] = rstds[bg * N_ + t];
  }
  float wc[64];
  const float* wp = Wc + ((size_t)(g * D_ + t)) * R_;
#pragma unroll
  for (int r4 = 0; r4 < 16; ++r4) {
    float4 w4 = *(const float4*)(wp + r4 * 4);
    wc[r4 * 4 + 0] = w4.x; wc[r4 * 4 + 1] = w4.y; wc[r4 * 4 + 2] = w4.z; wc[r4 * 4 + 3] = w4.w;
  }
  float gg = gv2[t], bb = bv2[t];
  __syncthreads();

  float acc[8] = {};
  for (int n = 0; n < N_; ++n) {
    const float4* vrow = (const float4*)&v1s[n * 64];
    float v = 0.f;
#pragma unroll
    for (int r4 = 0; r4 < 16; ++r4) {
      float4 vv = vrow[r4];
      v += wc[r4 * 4 + 0] * vv.x + wc[r4 * 4 + 1] * vv.y +
           wc[r4 * 4 + 2] * vv.z + wc[r4 * 4 + 3] * vv.w;
    }
    float l = (v - mean_s[n]) * rstd_s[n] * gg + bb;
    const float4* arow = (const float4*)&attn_s[(h * 256 + n) * 8];
    float4 a0 = arow[0], a1 = arow[1];
    acc[0] += a0.x * l; acc[1] += a0.y * l; acc[2] += a0.z * l; acc[3] += a0.w * l;
    acc[4] += a1.x * l; acc[5] += a1.y * l; acc[6] += a1.z * l; acc[7] += a1.w * l;
  }
#pragma unroll
  for (int rr = 0; rr < 8; ++rr)
    aout[((size_t)(b * NQ_ + rr * G_ + g)) * D_ + t] = acc[rr];
}

// ---------------- launch ----------------
extern "C" void kernel_launch(void* const* d_in, const int* in_sizes, int n_in,
                              void* d_out, int out_size, void* d_ws, size_t ws_size,
                              hipStream_t stream) {
  const float* x       = (const float*)d_in[0];
  const float* context = (const float*)d_in[1];
  const float* Wq  = (const float*)d_in[2];
  const float* gq  = (const float*)d_in[3];
  const float* bq  = (const float*)d_in[4];
  const float* Wk  = (const float*)d_in[5];
  const float* gk  = (const float*)d_in[6];
  const float* bk  = (const float*)d_in[7];
  const float* Wv1 = (const float*)d_in[8];
  const float* gv1 = (const float*)d_in[9];
  const float* bv1 = (const float*)d_in[10];
  const float* Wc  = (const float*)d_in[11];
  const float* gv2 = (const float*)d_in[12];
  const float* bv2 = (const float*)d_in[13];
  const float* Wout = (const float*)d_in[14];
  float* out = (float*)d_out;

  float* p = (float*)d_ws;
  float* q     = p; p += (size_t)B_ * NQ_ * D_;        // 1572864
  float* kT    = p; p += (size_t)B_ * H_ * DH_ * N_;   // 786432
  float* v1    = p; p += (size_t)B_ * N_ * MID_;       // 4194304
  float* attn  = p; p += (size_t)B_ * H_ * NQ_ * N_;   // 3145728
  float* means = p; p += (size_t)B_ * G_ * N_;         // 65536
  float* rstds = p; p += (size_t)B_ * G_ * N_;         // 65536
  float* aout  = p; p += (size_t)B_ * NQ_ * D_;        // 1572864 (also k-tmp)
  float* wcsum = p; p += (size_t)G_ * R_;              // 4096
  float* Msum  = p; p += (size_t)G_ * R_ * R_;         // 262144

  dim3 blk(256);
  // q = LN(x @ Wq) * scale
  sgemm_kernel<<<dim3(12, 16), blk, 0, stream>>>(x, Wq, q, 2048, D_, D_);
  ln_kernel<<<2048, blk, 0, stream>>>(q, q, gq, bq, D_, SCALE_);
  // kT = transpose(LN(context @ Wk) * scale)
  sgemm_kernel<<<dim3(12, 8), blk, 0, stream>>>(context, Wk, aout, 1024, D_, D_);
  ln_k_kernel<<<1024, blk, 0, stream>>>(aout, kT, gk, bk);
  // v1 = LN(context @ Wv1)
  sgemm_kernel<<<dim3(64, 8), blk, 0, stream>>>(context, Wv1, v1, 1024, D_, MID_);
  ln_kernel<<<1024, blk, 0, stream>>>(v1, v1, gv1, bv1, MID_, 1.0f);
  // LN stats of v via quadratic form (no v materialization)
  wprep_kernel<<<G_, blk, 0, stream>>>(Wc, wcsum, Msum);
  vstats_kernel<<<B_ * G_, blk, 0, stream>>>(v1, wcsum, Msum, means, rstds);
  // attention scores + softmax
  attn_kernel<<<dim3(NQ_ / 8, H_, B_), blk, 0, stream>>>(q, kT, attn);
  // fused grouped-conv + LN + PV
  pv_kernel<<<B_ * G_, dim3(768), 0, stream>>>(v1, Wc, attn, means, rstds, gv2, bv2, aout);
  // final projection
  sgemm_kernel<<<dim3(12, 16), blk, 0, stream>>>(aout, Wout, out, 2048, D_, D_);
}

// Round 3
// 622.115 us; speedup vs baseline: 2.3895x; 1.2726x over previous
//
#include <hip/hip_runtime.h>
#include <cstddef>

#define B_ 4
#define NQ_ 512
#define N_ 256
#define D_ 768
#define H_ 6
#define DH_ 128
#define G_ 64
#define R_ 64
#define MID_ 4096
#define VREP_ 8
#define EPS_ 1e-5f
#define SCALE_ 0.29730177875068026f  // 128^-0.25

typedef short bf16x8 __attribute__((ext_vector_type(8)));
typedef short short4v __attribute__((ext_vector_type(4)));
typedef float f32x4 __attribute__((ext_vector_type(4)));

__device__ __forceinline__ float b2f(short s) {
  union { float f; unsigned u; } c; c.u = ((unsigned)(unsigned short)s) << 16; return c.f;
}
__device__ __forceinline__ short f2b(float f) {
  union { float f; unsigned u; } c; c.f = f;
  unsigned r = c.u + 0x7FFFu + ((c.u >> 16) & 1u);
  return (short)(r >> 16);
}

#define AS1(p) ((const __attribute__((address_space(1))) unsigned int*)(p))
#define AS3(p) ((__attribute__((address_space(3))) unsigned int*)(p))

// ---------------- cast fp32 -> bf16 (4 elem/thread) ----------------
__global__ __launch_bounds__(256) void cast_kernel(const float* __restrict__ src,
                                                   short* __restrict__ dst, int n) {
  int i = (blockIdx.x * 256 + threadIdx.x) * 4;
  if (i < n) {
    float4 v = *(const float4*)&src[i];
    short4v o = {f2b(v.x), f2b(v.y), f2b(v.z), f2b(v.w)};
    *(short4v*)&dst[i] = o;
  }
}

// ---------------- transpose+cast: src fp32 [R][C] -> dst bf16 [C][R] ----------------
__global__ __launch_bounds__(256) void tcast_kernel(const float* __restrict__ src,
                                                    short* __restrict__ dst, int R, int C) {
  __shared__ float tile[32][33];
  int r0 = blockIdx.y * 32, c0 = blockIdx.x * 32;
  int t = threadIdx.x, tc = t & 31, tr = t >> 5;
#pragma unroll
  for (int i = 0; i < 4; ++i)
    tile[tr + i * 8][tc] = src[(size_t)(r0 + tr + i * 8) * C + c0 + tc];
  __syncthreads();
#pragma unroll
  for (int i = 0; i < 4; ++i)
    dst[(size_t)(c0 + tr + i * 8) * R + r0 + tc] = f2b(tile[tc][tr + i * 8]);
}

// ---------------- bf16 MFMA GEMM: C(f32 MxN) = A(bf16 MxK) @ BT(bf16 NxK) ----------------
// 128x128 tile, BK=32, 256 thr = 4 waves (64x64 quadrant each), global_load_lds 16B staging
__global__ __launch_bounds__(256, 2) void gemm_bf16_kernel(
    const short* __restrict__ A, const short* __restrict__ BT,
    float* __restrict__ C, int M, int N, int K) {
  __shared__ short As[128 * 32];
  __shared__ short Bs[128 * 32];
  int t = threadIdx.x, w = t >> 6, l = t & 63;
  int m0 = blockIdx.y * 128, n0 = blockIdx.x * 128;
  int wr = (w >> 1) * 64, wc = (w & 1) * 64;
  int lr = l & 15, lk = (l >> 4) * 8;
  f32x4 acc[4][4];
#pragma unroll
  for (int i = 0; i < 4; ++i)
#pragma unroll
    for (int j = 0; j < 4; ++j) acc[i][j] = (f32x4)0.f;

  int sr = t >> 2, sseg = (t & 3) * 8;  // staging: row, 16B segment
  const short* Ap = A + (size_t)(m0 + sr) * K + sseg;
  const short* Bp = BT + (size_t)(n0 + sr) * K + sseg;

  for (int k0 = 0; k0 < K; k0 += 32) {
    __builtin_amdgcn_global_load_lds(AS1(Ap + k0), AS3(&As[w * 512]), 16, 0, 0);
    __builtin_amdgcn_global_load_lds(AS1(Ap + (size_t)64 * K + k0), AS3(&As[2048 + w * 512]), 16, 0, 0);
    __builtin_amdgcn_global_load_lds(AS1(Bp + k0), AS3(&Bs[w * 512]), 16, 0, 0);
    __builtin_amdgcn_global_load_lds(AS1(Bp + (size_t)64 * K + k0), AS3(&Bs[2048 + w * 512]), 16, 0, 0);
    __syncthreads();
    bf16x8 af[4], bfr[4];
#pragma unroll
    for (int mi = 0; mi < 4; ++mi)
      af[mi] = *(const bf16x8*)&As[(wr + mi * 16 + lr) * 32 + lk];
#pragma unroll
    for (int ni = 0; ni < 4; ++ni)
      bfr[ni] = *(const bf16x8*)&Bs[(wc + ni * 16 + lr) * 32 + lk];
#pragma unroll
    for (int mi = 0; mi < 4; ++mi)
#pragma unroll
      for (int ni = 0; ni < 4; ++ni)
        acc[mi][ni] = __builtin_amdgcn_mfma_f32_16x16x32_bf16(af[mi], bfr[ni], acc[mi][ni], 0, 0, 0);
    __syncthreads();
  }
#pragma unroll
  for (int mi = 0; mi < 4; ++mi)
#pragma unroll
    for (int ni = 0; ni < 4; ++ni)
#pragma unroll
      for (int r = 0; r < 4; ++r)
        C[(size_t)(m0 + wr + mi * 16 + (l >> 4) * 4 + r) * N + n0 + wc + ni * 16 + lr] =
            acc[mi][ni][r];
}

// ---------------- block reduce (256 threads) ----------------
__device__ __forceinline__ void block_reduce2(float& s, float& q2, float* reds, float* redq) {
#pragma unroll
  for (int off = 32; off; off >>= 1) {
    s  += __shfl_down(s, off);
    q2 += __shfl_down(q2, off);
  }
  int w = threadIdx.x >> 6;
  if ((threadIdx.x & 63) == 0) { reds[w] = s; redq[w] = q2; }
  __syncthreads();
  s  = reds[0] + reds[1] + reds[2] + reds[3];
  q2 = redq[0] + redq[1] + redq[2] + redq[3];
}

// ---------------- LayerNorm fp32->fp32 with scale ----------------
__global__ __launch_bounds__(256) void ln_kernel(
    const float* in, float* outp,
    const float* __restrict__ gamma, const float* __restrict__ beta,
    int C, float scale) {
  __shared__ float reds[4], redq[4];
  int row = blockIdx.x;
  const float* xr = in + (size_t)row * C;
  float* orow = outp + (size_t)row * C;
  float s = 0.f, q2 = 0.f;
  for (int c = threadIdx.x; c < C; c += 256) {
    float v = xr[c]; s += v; q2 += v * v;
  }
  block_reduce2(s, q2, reds, redq);
  float mu = s / C;
  float var = q2 / C - mu * mu;
  float rstd = rsqrtf(var + EPS_);
  for (int c = threadIdx.x; c < C; c += 256)
    orow[c] = ((xr[c] - mu) * rstd * gamma[c] + beta[c]) * scale;
}

// ---------------- LN for k + transpose write (fp32): kT[b,h,d,j] ----------------
__global__ __launch_bounds__(256) void ln_k_kernel(
    const float* in, float* __restrict__ kT,
    const float* __restrict__ gamma, const float* __restrict__ beta) {
  __shared__ float reds[4], redq[4];
  int row = blockIdx.x;  // b*N + j
  int b = row >> 8, j = row & 255;
  const float* xr = in + (size_t)row * D_;
  float s = 0.f, q2 = 0.f;
  for (int c = threadIdx.x; c < D_; c += 256) {
    float v = xr[c]; s += v; q2 += v * v;
  }
  block_reduce2(s, q2, reds, redq);
  float mu = s / D_;
  float var = q2 / D_ - mu * mu;
  float rstd = rsqrtf(var + EPS_);
  for (int c = threadIdx.x; c < D_; c += 256) {
    float val = ((xr[c] - mu) * rstd * gamma[c] + beta[c]) * SCALE_;
    int h = c >> 7, dd = c & 127;
    kT[((size_t)((b * H_ + h) * DH_ + dd)) * N_ + j] = val;
  }
}

// ---------------- LN fp32 -> bf16 (for v1), C = 4096 ----------------
__global__ __launch_bounds__(256) void ln_v1_kernel(
    const float* in, short* __restrict__ outp,
    const float* __restrict__ gamma, const float* __restrict__ beta) {
  __shared__ float reds[4], redq[4];
  int row = blockIdx.x;
  const float* xr = in + (size_t)row * MID_;
  short* orow = outp + (size_t)row * MID_;
  float s = 0.f, q2 = 0.f;
  for (int c = threadIdx.x; c < MID_; c += 256) {
    float v = xr[c]; s += v; q2 += v * v;
  }
  block_reduce2(s, q2, reds, redq);
  float mu = s / MID_;
  float var = q2 / MID_ - mu * mu;
  float rstd = rsqrtf(var + EPS_);
  for (int c = threadIdx.x; c < MID_; c += 256)
    orow[c] = f2b((xr[c] - mu) * rstd * gamma[c] + beta[c]);
}

// ---------------- Wc prep (reads bf16 Wcb to match bf16 conv) ----------------
__global__ __launch_bounds__(256) void wprep_kernel(
    const short* __restrict__ Wcb, float* __restrict__ wcsum, float* __restrict__ Msum) {
  __shared__ __align__(16) float wd[16][64];
  int g = blockIdx.x, t = threadIdx.x;
  int r1 = t >> 2, r2b = (t & 3) * 16;
  float acc[16] = {};
  float wsum = 0.f;
  for (int d0 = 0; d0 < D_; d0 += 16) {
    for (int idx = t; idx < 1024; idx += 256)
      wd[idx >> 6][idx & 63] = b2f(Wcb[((size_t)g * D_ + d0 + (idx >> 6)) * R_ + (idx & 63)]);
    __syncthreads();
#pragma unroll 4
    for (int i = 0; i < 16; ++i) {
      float a = wd[i][r1];
#pragma unroll
      for (int kk = 0; kk < 16; ++kk) acc[kk] += a * wd[i][r2b + kk];
    }
    if (t < 64) {
#pragma unroll 4
      for (int i = 0; i < 16; ++i) wsum += wd[i][t];
    }
    __syncthreads();
  }
  const float inv = 1.f / (float)D_;
#pragma unroll
  for (int kk = 0; kk < 16; ++kk)
    Msum[(size_t)g * 4096 + r1 * 64 + r2b + kk] = acc[kk] * inv;
  if (t < 64) wcsum[g * 64 + t] = wsum * inv;
}

// ---------------- v stats (reads bf16 v1) ----------------
__global__ __launch_bounds__(256) void vstats_kernel(
    const short* __restrict__ v1b, const float* __restrict__ wcsum,
    const float* __restrict__ Msum, float* __restrict__ means, float* __restrict__ rstds) {
  __shared__ __align__(16) float Ms[4096];
  __shared__ float ws[64];
  int bg = blockIdx.x;
  int b = bg >> 6, g = bg & 63;
  int t = threadIdx.x;
  for (int idx = t; idx < 4096; idx += 256) Ms[idx] = Msum[(size_t)g * 4096 + idx];
  if (t < 64) ws[t] = wcsum[g * 64 + t];
  __syncthreads();
  const short* vp = v1b + ((size_t)(b * N_ + t)) * MID_ + g * R_;
  float v[64];
#pragma unroll
  for (int r8 = 0; r8 < 8; ++r8) {
    bf16x8 x = *(const bf16x8*)&vp[r8 * 8];
#pragma unroll
    for (int j = 0; j < 8; ++j) v[r8 * 8 + j] = b2f(x[j]);
  }
  float mu = 0.f;
#pragma unroll
  for (int r = 0; r < 64; ++r) mu += v[r] * ws[r];
  float msq = 0.f;
#pragma unroll
  for (int r1 = 0; r1 < 64; ++r1) {
    const float4* mrow = (const float4*)&Ms[r1 * 64];
    float ts = 0.f;
#pragma unroll
    for (int r2 = 0; r2 < 16; ++r2) {
      float4 m4 = mrow[r2];
      ts += m4.x * v[r2 * 4] + m4.y * v[r2 * 4 + 1] + m4.z * v[r2 * 4 + 2] + m4.w * v[r2 * 4 + 3];
    }
    msq += v[r1] * ts;
  }
  float var = msq - mu * mu;
  means[bg * N_ + t] = mu;
  rstds[bg * N_ + t] = rsqrtf(var + EPS_);
}

// ---------------- attention scores + softmax (fp32) ----------------
__global__ __launch_bounds__(256) void attn_kernel(
    const float* __restrict__ q, const float* __restrict__ kT, float* __restrict__ attn) {
  __shared__ __align__(16) float qs[8][128];
  __shared__ float sims[8][256];
  int b = blockIdx.z, h = blockIdx.y, i0 = blockIdx.x * 8;
  int t = threadIdx.x;
  for (int idx = t; idx < 1024; idx += 256) {
    int rr = idx >> 7, d = idx & 127;
    qs[rr][d] = q[((size_t)(b * NQ_ + i0 + rr)) * D_ + h * DH_ + d];
  }
  __syncthreads();
  const float* kp = kT + ((size_t)(b * H_ + h) * DH_) * N_ + t;
  float sim[8] = {};
  for (int d4 = 0; d4 < 32; ++d4) {
    float kv0 = kp[(d4 * 4 + 0) * N_];
    float kv1 = kp[(d4 * 4 + 1) * N_];
    float kv2 = kp[(d4 * 4 + 2) * N_];
    float kv3 = kp[(d4 * 4 + 3) * N_];
#pragma unroll
    for (int r = 0; r < 8; ++r) {
      float4 qv = *(const float4*)&qs[r][d4 * 4];
      sim[r] += qv.x * kv0 + qv.y * kv1 + qv.z * kv2 + qv.w * kv3;
    }
  }
#pragma unroll
  for (int r = 0; r < 8; ++r) sims[r][t] = sim[r];
  __syncthreads();
  int w = t >> 6, lane = t & 63;
#pragma unroll
  for (int rr = 0; rr < 2; ++rr) {
    int r = w * 2 + rr;
    float v0 = sims[r][lane], v1v = sims[r][lane + 64];
    float v2 = sims[r][lane + 128], v3 = sims[r][lane + 192];
    float mx = fmaxf(fmaxf(v0, v1v), fmaxf(v2, v3));
#pragma unroll
    for (int off = 32; off; off >>= 1) mx = fmaxf(mx, __shfl_xor(mx, off));
    float e0 = expf(v0 - mx), e1 = expf(v1v - mx), e2 = expf(v2 - mx), e3 = expf(v3 - mx);
    float s = e0 + e1 + e2 + e3;
#pragma unroll
    for (int off = 32; off; off >>= 1) s += __shfl_xor(s, off);
    float inv = 1.f / s;
    float* ap = attn + ((size_t)((b * H_ + h) * NQ_ + i0 + r)) * N_;
    ap[lane] = e0 * inv; ap[lane + 64] = e1 * inv;
    ap[lane + 128] = e2 * inv; ap[lane + 192] = e3 * inv;
  }
}

// ---------------- fused conv+LN+PV via MFMA: block per (b,g), 256 thr = 4 waves ----------------
// per d-chunk of 128 (= head ci): conv C1[256n x 128d] = V1s @ Wc^T, LN epilogue -> Ls[d][n] bf16,
// PV: out[8rr x 128d] = attn(8x256) @ L. Strides padded to 16B multiples for ds_*_b128.
#define LV1 72
#define LLS 264
__global__ __launch_bounds__(256, 1) void pv_mfma_kernel(
    const short* __restrict__ v1b, const short* __restrict__ Wcb,
    const float* __restrict__ attn, const float* __restrict__ means,
    const float* __restrict__ rstds, const float* __restrict__ gv2,
    const float* __restrict__ bv2, short* __restrict__ aoutb) {
  __shared__ short V1s[256 * LV1];   // 36.9KB [n][r]
  __shared__ short Wcs[128 * LV1];   // 18.4KB [d][r] (per chunk)
  __shared__ short Ls[128 * LLS];    // 67.6KB [d][n] (per chunk)
  __shared__ short As2[56 * LLS];    // 29.6KB [i=h*8+rr][n]
  __shared__ float mean_s[256], rstd_s[256];
  int bg = blockIdx.x, b = bg >> 6, g = bg & 63;
  int t = threadIdx.x, w = t >> 6, l = t & 63;
  int lr = l & 15, lk = (l >> 4) * 8;

  // stage V1 slice (bf16): [256][64] -> V1s[n][r]
#pragma unroll
  for (int it = 0; it < 8; ++it) {
    int idx = it * 256 + t;
    int n = idx >> 3, seg = (idx & 7) * 8;
    bf16x8 v = *(const bf16x8*)&v1b[((size_t)(b * N_ + n)) * MID_ + g * R_ + seg];
    *(bf16x8*)&V1s[n * LV1 + seg] = v;
  }
  // stage attn rows (48) fp32->bf16: As2[h*8+rr][n]
#pragma unroll
  for (int it = 0; it < 12; ++it) {
    int idx = it * 256 + t;
    int i = idx >> 6, c4 = (idx & 63) * 4;
    int h = i >> 3, rr = i & 7;
    float4 a4 = *(const float4*)&attn[((size_t)((b * H_ + h) * NQ_ + rr * G_ + g)) * N_ + c4];
    short4v o = {f2b(a4.x), f2b(a4.y), f2b(a4.z), f2b(a4.w)};
    *(short4v*)&As2[i * LLS + c4] = o;
  }
  // zero pad rows 48..55 of As2 (read by the M=16 frag at ci=5)
  for (int idx = t; idx < 8 * LLS; idx += 256) As2[48 * LLS + idx] = 0;
  mean_s[t] = means[bg * N_ + t];
  rstd_s[t] = rstds[bg * N_ + t];

  // prologue: stage Wcs for chunk 0
#pragma unroll
  for (int it = 0; it < 4; ++it) {
    int idx = it * 256 + t;
    int dd = idx >> 3, seg = (idx & 7) * 8;
    bf16x8 v = *(const bf16x8*)&Wcb[((size_t)g * D_ + dd) * R_ + seg];
    *(bf16x8*)&Wcs[dd * LV1 + seg] = v;
  }
  __syncthreads();

  for (int ci = 0; ci < 6; ++ci) {
    int d0 = ci * 128;
    // ---- conv: wave w owns n-rows [w*64, w*64+64) x all 128 d ----
    f32x4 cacc[4][8];
#pragma unroll
    for (int mi = 0; mi < 4; ++mi)
#pragma unroll
      for (int ni = 0; ni < 8; ++ni) cacc[mi][ni] = (f32x4)0.f;
#pragma unroll
    for (int k0 = 0; k0 < 64; k0 += 32) {
      bf16x8 af[4];
#pragma unroll
      for (int mi = 0; mi < 4; ++mi)
        af[mi] = *(const bf16x8*)&V1s[(w * 64 + mi * 16 + lr) * LV1 + k0 + lk];
#pragma unroll
      for (int ni = 0; ni < 8; ++ni) {
        bf16x8 bfr = *(const bf16x8*)&Wcs[(ni * 16 + lr) * LV1 + k0 + lk];
#pragma unroll
        for (int mi = 0; mi < 4; ++mi)
          cacc[mi][ni] = __builtin_amdgcn_mfma_f32_16x16x32_bf16(af[mi], bfr, cacc[mi][ni], 0, 0, 0);
      }
    }
    // ---- LN epilogue -> Ls[d][n] bf16 ----
    float mn[4][4], rs[4][4];
#pragma unroll
    for (int mi = 0; mi < 4; ++mi)
#pragma unroll
      for (int r = 0; r < 4; ++r) {
        int nrow = w * 64 + mi * 16 + (l >> 4) * 4 + r;
        mn[mi][r] = mean_s[nrow];
        rs[mi][r] = rstd_s[nrow];
      }
    float gc[8], bc[8];
#pragma unroll
    for (int ni = 0; ni < 8; ++ni) {
      gc[ni] = gv2[d0 + ni * 16 + lr];
      bc[ni] = bv2[d0 + ni * 16 + lr];
    }
#pragma unroll
    for (int mi = 0; mi < 4; ++mi)
#pragma unroll
      for (int ni = 0; ni < 8; ++ni) {
        f32x4 c = cacc[mi][ni];
        short4v o = {f2b((c[0] - mn[mi][0]) * rs[mi][0] * gc[ni] + bc[ni]),
                     f2b((c[1] - mn[mi][1]) * rs[mi][1] * gc[ni] + bc[ni]),
                     f2b((c[2] - mn[mi][2]) * rs[mi][2] * gc[ni] + bc[ni]),
                     f2b((c[3] - mn[mi][3]) * rs[mi][3] * gc[ni] + bc[ni])};
        *(short4v*)&Ls[(ni * 16 + lr) * LLS + w * 64 + mi * 16 + (l >> 4) * 4] = o;
      }
    __syncthreads();  // Ls complete; Wcs free

    // ---- PV: wave w owns d-cols [w*32, w*32+32); A rows = head ci ----
    f32x4 acc2[2];
    acc2[0] = (f32x4)0.f; acc2[1] = (f32x4)0.f;
#pragma unroll
    for (int k0 = 0; k0 < 256; k0 += 32) {
      bf16x8 paf = *(const bf16x8*)&As2[(ci * 8 + lr) * LLS + k0 + lk];
#pragma unroll
      for (int nf = 0; nf < 2; ++nf) {
        bf16x8 pbf = *(const bf16x8*)&Ls[(w * 32 + nf * 16 + lr) * LLS + k0 + lk];
        acc2[nf] = __builtin_amdgcn_mfma_f32_16x16x32_bf16(paf, pbf, acc2[nf], 0, 0, 0);
      }
    }
    // stage next chunk's Wcs (overlaps PV epilogue; Wcs unused until after barrier)
    if (ci < 5) {
#pragma unroll
      for (int it = 0; it < 4; ++it) {
        int idx = it * 256 + t;
        int dd = idx >> 3, seg = (idx & 7) * 8;
        bf16x8 v = *(const bf16x8*)&Wcb[((size_t)g * D_ + d0 + 128 + dd) * R_ + seg];
        *(bf16x8*)&Wcs[dd * LV1 + seg] = v;
      }
    }
    // write output rows rr=0..7 (lanes 0..31)
    if (l < 32) {
#pragma unroll
      for (int nf = 0; nf < 2; ++nf)
#pragma unroll
        for (int r = 0; r < 4; ++r) {
          int rr = (l >> 4) * 4 + r;
          int dcol = d0 + w * 32 + nf * 16 + lr;
          aoutb[((size_t)(b * NQ_ + rr * G_ + g)) * D_ + dcol] = f2b(acc2[nf][r]);
        }
    }
    __syncthreads();  // Wcs ready, Ls free
  }
}

// ---------------- launch ----------------
extern "C" void kernel_launch(void* const* d_in, const int* in_sizes, int n_in,
                              void* d_out, int out_size, void* d_ws, size_t ws_size,
                              hipStream_t stream) {
  const float* x       = (const float*)d_in[0];
  const float* context = (const float*)d_in[1];
  const float* Wq  = (const float*)d_in[2];
  const float* gq  = (const float*)d_in[3];
  const float* bq  = (const float*)d_in[4];
  const float* Wk  = (const float*)d_in[5];
  const float* gk  = (const float*)d_in[6];
  const float* bk  = (const float*)d_in[7];
  const float* Wv1 = (const float*)d_in[8];
  const float* gv1 = (const float*)d_in[9];
  const float* bv1 = (const float*)d_in[10];
  const float* Wc  = (const float*)d_in[11];
  const float* gv2 = (const float*)d_in[12];
  const float* bv2 = (const float*)d_in[13];
  const float* Wout = (const float*)d_in[14];
  float* out = (float*)d_out;

  char* p = (char*)d_ws;
  float* tmp   = (float*)p; p += (size_t)4194304 * 4;   // 16.8MB gemm out (reused)
  float* q     = (float*)p; p += (size_t)1572864 * 4;
  float* kT    = (float*)p; p += (size_t)786432 * 4;
  float* attn  = (float*)p; p += (size_t)3145728 * 4;
  float* means = (float*)p; p += (size_t)65536 * 4;
  float* rstds = (float*)p; p += (size_t)65536 * 4;
  float* wcsum = (float*)p; p += (size_t)4096 * 4;
  float* Msum  = (float*)p; p += (size_t)262144 * 4;
  short* xb    = (short*)p; p += (size_t)1572864 * 2;
  short* cb    = (short*)p; p += (size_t)786432 * 2;
  short* WqT   = (short*)p; p += (size_t)589824 * 2;
  short* WkT   = (short*)p; p += (size_t)589824 * 2;
  short* Wv1T  = (short*)p; p += (size_t)3145728 * 2;
  short* WoutT = (short*)p; p += (size_t)589824 * 2;
  short* Wcb   = (short*)p; p += (size_t)3145728 * 2;
  short* v1b   = (short*)p; p += (size_t)4194304 * 2;
  short* aoutb = (short*)p; p += (size_t)1572864 * 2;

  dim3 blk(256);
  // casts / transposes
  cast_kernel<<<1536, blk, 0, stream>>>(x, xb, 1572864);
  cast_kernel<<<768, blk, 0, stream>>>(context, cb, 786432);
  cast_kernel<<<3072, blk, 0, stream>>>(Wc, Wcb, 3145728);
  tcast_kernel<<<dim3(24, 24), blk, 0, stream>>>(Wq, WqT, 768, 768);
  tcast_kernel<<<dim3(24, 24), blk, 0, stream>>>(Wk, WkT, 768, 768);
  tcast_kernel<<<dim3(128, 24), blk, 0, stream>>>(Wv1, Wv1T, 768, 4096);
  tcast_kernel<<<dim3(24, 24), blk, 0, stream>>>(Wout, WoutT, 768, 768);
  // q = LN(x @ Wq) * scale   (fp32 q for fp32 attn)
  gemm_bf16_kernel<<<dim3(6, 16), blk, 0, stream>>>(xb, WqT, tmp, 2048, 768, 768);
  ln_kernel<<<2048, blk, 0, stream>>>(tmp, q, gq, bq, 768, SCALE_);
  // kT = LN(ctx @ Wk) * scale, transposed
  gemm_bf16_kernel<<<dim3(6, 8), blk, 0, stream>>>(cb, WkT, tmp, 1024, 768, 768);
  ln_k_kernel<<<1024, blk, 0, stream>>>(tmp, kT, gk, bk);
  // v1 = LN(ctx @ Wv1) -> bf16
  gemm_bf16_kernel<<<dim3(32, 8), blk, 0, stream>>>(cb, Wv1T, tmp, 1024, 4096, 768);
  ln_v1_kernel<<<1024, blk, 0, stream>>>(tmp, v1b, gv1, bv1);
  // v LN stats via quadratic form (bf16-consistent)
  wprep_kernel<<<G_, blk, 0, stream>>>(Wcb, wcsum, Msum);
  vstats_kernel<<<B_ * G_, blk, 0, stream>>>(v1b, wcsum, Msum, means, rstds);
  // attention (fp32)
  attn_kernel<<<dim3(64, 6, 4), blk, 0, stream>>>(q, kT, attn);
  // fused conv+LN+PV (MFMA)
  pv_mfma_kernel<<<256, blk, 0, stream>>>(v1b, Wcb, attn, means, rstds, gv2, bv2, aoutb);
  // final projection
  gemm_bf16_kernel<<<dim3(6, 16), blk, 0, stream>>>(aoutb, WoutT, out, 2048, 768, 768);
}

// Round 4
// 282.203 us; speedup vs baseline: 5.2675x; 2.2045x over previous
//
#include <hip/hip_runtime.h>
#include <cstddef>

#define B_ 4
#define NQ_ 512
#define N_ 256
#define D_ 768
#define H_ 6
#define DH_ 128
#define G_ 64
#define R_ 64
#define MID_ 4096
#define VREP_ 8
#define EPS_ 1e-5f
#define SCALE_ 0.29730177875068026f  // 128^-0.25

typedef short bf16x8 __attribute__((ext_vector_type(8)));
typedef short short4v __attribute__((ext_vector_type(4)));
typedef float f32x4 __attribute__((ext_vector_type(4)));

__device__ __forceinline__ float b2f(short s) {
  union { float f; unsigned u; } c; c.u = ((unsigned)(unsigned short)s) << 16; return c.f;
}
__device__ __forceinline__ short f2b(float f) {
  union { float f; unsigned u; } c; c.f = f;
  unsigned r = c.u + 0x7FFFu + ((c.u >> 16) & 1u);
  return (short)(r >> 16);
}

#define AS1(p) ((const __attribute__((address_space(1))) unsigned int*)(p))
#define AS3(p) ((__attribute__((address_space(3))) unsigned int*)(p))

// ---------------- cast fp32 -> bf16 (4 elem/thread) ----------------
__global__ __launch_bounds__(256) void cast_kernel(const float* __restrict__ src,
                                                   short* __restrict__ dst, int n) {
  int i = (blockIdx.x * 256 + threadIdx.x) * 4;
  if (i < n) {
    float4 v = *(const float4*)&src[i];
    short4v o = {f2b(v.x), f2b(v.y), f2b(v.z), f2b(v.w)};
    *(short4v*)&dst[i] = o;
  }
}

// ---------------- transpose+cast: src fp32 [R][C] -> dst bf16 [C][R] ----------------
__global__ __launch_bounds__(256) void tcast_kernel(const float* __restrict__ src,
                                                    short* __restrict__ dst, int R, int C) {
  __shared__ float tile[32][33];
  int r0 = blockIdx.y * 32, c0 = blockIdx.x * 32;
  int t = threadIdx.x, tc = t & 31, tr = t >> 5;
#pragma unroll
  for (int i = 0; i < 4; ++i)
    tile[tr + i * 8][tc] = src[(size_t)(r0 + tr + i * 8) * C + c0 + tc];
  __syncthreads();
#pragma unroll
  for (int i = 0; i < 4; ++i)
    dst[(size_t)(c0 + tr + i * 8) * R + r0 + tc] = f2b(tile[tc][tr + i * 8]);
}

// ---------------- bf16 MFMA GEMM: C(f32 MxN) = A(bf16 MxK) @ BT(bf16 NxK) ----------------
// 128x128 tile, BK=32, 256 thr = 4 waves (64x64 quadrant each), global_load_lds 16B staging
__global__ __launch_bounds__(256, 2) void gemm_bf16_kernel(
    const short* __restrict__ A, const short* __restrict__ BT,
    float* __restrict__ C, int M, int N, int K) {
  __shared__ short As[128 * 32];
  __shared__ short Bs[128 * 32];
  int t = threadIdx.x, w = t >> 6, l = t & 63;
  int m0 = blockIdx.y * 128, n0 = blockIdx.x * 128;
  int wr = (w >> 1) * 64, wc = (w & 1) * 64;
  int lr = l & 15, lk = (l >> 4) * 8;
  f32x4 acc[4][4];
#pragma unroll
  for (int i = 0; i < 4; ++i)
#pragma unroll
    for (int j = 0; j < 4; ++j) acc[i][j] = (f32x4)0.f;

  int sr = t >> 2, sseg = (t & 3) * 8;  // staging: row, 16B segment
  const short* Ap = A + (size_t)(m0 + sr) * K + sseg;
  const short* Bp = BT + (size_t)(n0 + sr) * K + sseg;

  for (int k0 = 0; k0 < K; k0 += 32) {
    __builtin_amdgcn_global_load_lds(AS1(Ap + k0), AS3(&As[w * 512]), 16, 0, 0);
    __builtin_amdgcn_global_load_lds(AS1(Ap + (size_t)64 * K + k0), AS3(&As[2048 + w * 512]), 16, 0, 0);
    __builtin_amdgcn_global_load_lds(AS1(Bp + k0), AS3(&Bs[w * 512]), 16, 0, 0);
    __builtin_amdgcn_global_load_lds(AS1(Bp + (size_t)64 * K + k0), AS3(&Bs[2048 + w * 512]), 16, 0, 0);
    __syncthreads();
    bf16x8 af[4], bfr[4];
#pragma unroll
    for (int mi = 0; mi < 4; ++mi)
      af[mi] = *(const bf16x8*)&As[(wr + mi * 16 + lr) * 32 + lk];
#pragma unroll
    for (int ni = 0; ni < 4; ++ni)
      bfr[ni] = *(const bf16x8*)&Bs[(wc + ni * 16 + lr) * 32 + lk];
#pragma unroll
    for (int mi = 0; mi < 4; ++mi)
#pragma unroll
      for (int ni = 0; ni < 4; ++ni)
        acc[mi][ni] = __builtin_amdgcn_mfma_f32_16x16x32_bf16(af[mi], bfr[ni], acc[mi][ni], 0, 0, 0);
    __syncthreads();
  }
#pragma unroll
  for (int mi = 0; mi < 4; ++mi)
#pragma unroll
    for (int ni = 0; ni < 4; ++ni)
#pragma unroll
      for (int r = 0; r < 4; ++r)
        C[(size_t)(m0 + wr + mi * 16 + (l >> 4) * 4 + r) * N + n0 + wc + ni * 16 + lr] =
            acc[mi][ni][r];
}

// ---------------- block reduce (256 threads) ----------------
__device__ __forceinline__ void block_reduce2(float& s, float& q2, float* reds, float* redq) {
#pragma unroll
  for (int off = 32; off; off >>= 1) {
    s  += __shfl_down(s, off);
    q2 += __shfl_down(q2, off);
  }
  int w = threadIdx.x >> 6;
  if ((threadIdx.x & 63) == 0) { reds[w] = s; redq[w] = q2; }
  __syncthreads();
  s  = reds[0] + reds[1] + reds[2] + reds[3];
  q2 = redq[0] + redq[1] + redq[2] + redq[3];
}

// ---------------- LayerNorm fp32->fp32 with scale ----------------
__global__ __launch_bounds__(256) void ln_kernel(
    const float* in, float* outp,
    const float* __restrict__ gamma, const float* __restrict__ beta,
    int C, float scale) {
  __shared__ float reds[4], redq[4];
  int row = blockIdx.x;
  const float* xr = in + (size_t)row * C;
  float* orow = outp + (size_t)row * C;
  float s = 0.f, q2 = 0.f;
  for (int c = threadIdx.x; c < C; c += 256) {
    float v = xr[c]; s += v; q2 += v * v;
  }
  block_reduce2(s, q2, reds, redq);
  float mu = s / C;
  float var = q2 / C - mu * mu;
  float rstd = rsqrtf(var + EPS_);
  for (int c = threadIdx.x; c < C; c += 256)
    orow[c] = ((xr[c] - mu) * rstd * gamma[c] + beta[c]) * scale;
}

// ---------------- LN for k + transpose write (fp32): kT[b,h,d,j] ----------------
__global__ __launch_bounds__(256) void ln_k_kernel(
    const float* in, float* __restrict__ kT,
    const float* __restrict__ gamma, const float* __restrict__ beta) {
  __shared__ float reds[4], redq[4];
  int row = blockIdx.x;  // b*N + j
  int b = row >> 8, j = row & 255;
  const float* xr = in + (size_t)row * D_;
  float s = 0.f, q2 = 0.f;
  for (int c = threadIdx.x; c < D_; c += 256) {
    float v = xr[c]; s += v; q2 += v * v;
  }
  block_reduce2(s, q2, reds, redq);
  float mu = s / D_;
  float var = q2 / D_ - mu * mu;
  float rstd = rsqrtf(var + EPS_);
  for (int c = threadIdx.x; c < D_; c += 256) {
    float val = ((xr[c] - mu) * rstd * gamma[c] + beta[c]) * SCALE_;
    int h = c >> 7, dd = c & 127;
    kT[((size_t)((b * H_ + h) * DH_ + dd)) * N_ + j] = val;
  }
}

// ---------------- LN fp32 -> bf16 (for v1), C = 4096 ----------------
__global__ __launch_bounds__(256) void ln_v1_kernel(
    const float* in, short* __restrict__ outp,
    const float* __restrict__ gamma, const float* __restrict__ beta) {
  __shared__ float reds[4], redq[4];
  int row = blockIdx.x;
  const float* xr = in + (size_t)row * MID_;
  short* orow = outp + (size_t)row * MID_;
  float s = 0.f, q2 = 0.f;
  for (int c = threadIdx.x; c < MID_; c += 256) {
    float v = xr[c]; s += v; q2 += v * v;
  }
  block_reduce2(s, q2, reds, redq);
  float mu = s / MID_;
  float var = q2 / MID_ - mu * mu;
  float rstd = rsqrtf(var + EPS_);
  for (int c = threadIdx.x; c < MID_; c += 256)
    orow[c] = f2b((xr[c] - mu) * rstd * gamma[c] + beta[c]);
}

// ---------------- attention scores + softmax (fp32) ----------------
__global__ __launch_bounds__(256) void attn_kernel(
    const float* __restrict__ q, const float* __restrict__ kT, float* __restrict__ attn) {
  __shared__ __align__(16) float qs[8][128];
  __shared__ float sims[8][256];
  int b = blockIdx.z, h = blockIdx.y, i0 = blockIdx.x * 8;
  int t = threadIdx.x;
  for (int idx = t; idx < 1024; idx += 256) {
    int rr = idx >> 7, d = idx & 127;
    qs[rr][d] = q[((size_t)(b * NQ_ + i0 + rr)) * D_ + h * DH_ + d];
  }
  __syncthreads();
  const float* kp = kT + ((size_t)(b * H_ + h) * DH_) * N_ + t;
  float sim[8] = {};
  for (int d4 = 0; d4 < 32; ++d4) {
    float kv0 = kp[(d4 * 4 + 0) * N_];
    float kv1 = kp[(d4 * 4 + 1) * N_];
    float kv2 = kp[(d4 * 4 + 2) * N_];
    float kv3 = kp[(d4 * 4 + 3) * N_];
#pragma unroll
    for (int r = 0; r < 8; ++r) {
      float4 qv = *(const float4*)&qs[r][d4 * 4];
      sim[r] += qv.x * kv0 + qv.y * kv1 + qv.z * kv2 + qv.w * kv3;
    }
  }
#pragma unroll
  for (int r = 0; r < 8; ++r) sims[r][t] = sim[r];
  __syncthreads();
  int w = t >> 6, lane = t & 63;
#pragma unroll
  for (int rr = 0; rr < 2; ++rr) {
    int r = w * 2 + rr;
    float v0 = sims[r][lane], v1v = sims[r][lane + 64];
    float v2 = sims[r][lane + 128], v3 = sims[r][lane + 192];
    float mx = fmaxf(fmaxf(v0, v1v), fmaxf(v2, v3));
#pragma unroll
    for (int off = 32; off; off >>= 1) mx = fmaxf(mx, __shfl_xor(mx, off));
    float e0 = expf(v0 - mx), e1 = expf(v1v - mx), e2 = expf(v2 - mx), e3 = expf(v3 - mx);
    float s = e0 + e1 + e2 + e3;
#pragma unroll
    for (int off = 32; off; off >>= 1) s += __shfl_xor(s, off);
    float inv = 1.f / s;
    float* ap = attn + ((size_t)((b * H_ + h) * NQ_ + i0 + r)) * N_;
    ap[lane] = e0 * inv; ap[lane + 64] = e1 * inv;
    ap[lane + 128] = e2 * inv; ap[lane + 192] = e3 * inv;
  }
}

// ---------------- fused conv+LN+PV via MFMA: block per (b,g), 256 thr = 4 waves ----------------
// PASS 1: conv over 6 d-chunks, accumulate per-n sum/sumsq in registers (lane-partial over its
//         d-subset), butterfly-reduce over the 16-lane col group -> mean/rstd in LDS.
//         (replaces the spill-bound vstats quadratic-form kernel: stats are now bitwise-
//          consistent with pass-2 conv values, and MFMA recompute is ~free.)
// PASS 2: per chunk: conv -> LN epilogue -> Ls[d][n] bf16 -> PV (attn @ L) -> out.
#define LV1 72
#define LLS 264
__global__ __launch_bounds__(256, 1) void pv_mfma_kernel(
    const short* __restrict__ v1b, const short* __restrict__ Wcb,
    const float* __restrict__ attn, const float* __restrict__ gv2,
    const float* __restrict__ bv2, short* __restrict__ aoutb) {
  __shared__ short V1s[256 * LV1];   // 36.9KB [n][r]
  __shared__ short Wcs[128 * LV1];   // 18.4KB [d][r] (per chunk)
  __shared__ short Ls[128 * LLS];    // 67.6KB [d][n] (per chunk)
  __shared__ short As2[56 * LLS];    // 29.6KB [i=h*8+rr][n]
  __shared__ float mean_s[256], rstd_s[256];
  int bg = blockIdx.x, b = bg >> 6, g = bg & 63;
  int t = threadIdx.x, w = t >> 6, l = t & 63;
  int lr = l & 15, lk = (l >> 4) * 8;

  // stage V1 slice (bf16): [256][64] -> V1s[n][r]
#pragma unroll
  for (int it = 0; it < 8; ++it) {
    int idx = it * 256 + t;
    int n = idx >> 3, seg = (idx & 7) * 8;
    bf16x8 v = *(const bf16x8*)&v1b[((size_t)(b * N_ + n)) * MID_ + g * R_ + seg];
    *(bf16x8*)&V1s[n * LV1 + seg] = v;
  }
  // stage attn rows (48) fp32->bf16: As2[h*8+rr][n]
#pragma unroll
  for (int it = 0; it < 12; ++it) {
    int idx = it * 256 + t;
    int i = idx >> 6, c4 = (idx & 63) * 4;
    int h = i >> 3, rr = i & 7;
    float4 a4 = *(const float4*)&attn[((size_t)((b * H_ + h) * NQ_ + rr * G_ + g)) * N_ + c4];
    short4v o = {f2b(a4.x), f2b(a4.y), f2b(a4.z), f2b(a4.w)};
    *(short4v*)&As2[i * LLS + c4] = o;
  }
  // zero pad rows 48..55 of As2 (read by the M=16 frag at ci=5)
  for (int idx = t; idx < 8 * LLS; idx += 256) As2[48 * LLS + idx] = 0;

  // ======== PASS 1: conv-only, accumulate stats ========
  float sum_[4][4], sq_[4][4];
#pragma unroll
  for (int mi = 0; mi < 4; ++mi)
#pragma unroll
    for (int r = 0; r < 4; ++r) { sum_[mi][r] = 0.f; sq_[mi][r] = 0.f; }

  for (int ci = 0; ci < 6; ++ci) {
#pragma unroll
    for (int it = 0; it < 4; ++it) {
      int idx = it * 256 + t;
      int dd = idx >> 3, seg = (idx & 7) * 8;
      bf16x8 v = *(const bf16x8*)&Wcb[((size_t)g * D_ + ci * 128 + dd) * R_ + seg];
      *(bf16x8*)&Wcs[dd * LV1 + seg] = v;
    }
    __syncthreads();
#pragma unroll
    for (int nb = 0; nb < 2; ++nb) {  // ni blocks of 4 (keeps VGPR low in pass 1)
      f32x4 cacc[4][4];
#pragma unroll
      for (int mi = 0; mi < 4; ++mi)
#pragma unroll
        for (int nj = 0; nj < 4; ++nj) cacc[mi][nj] = (f32x4)0.f;
#pragma unroll
      for (int k0 = 0; k0 < 64; k0 += 32) {
        bf16x8 af[4];
#pragma unroll
        for (int mi = 0; mi < 4; ++mi)
          af[mi] = *(const bf16x8*)&V1s[(w * 64 + mi * 16 + lr) * LV1 + k0 + lk];
#pragma unroll
        for (int nj = 0; nj < 4; ++nj) {
          bf16x8 bfr = *(const bf16x8*)&Wcs[((nb * 4 + nj) * 16 + lr) * LV1 + k0 + lk];
#pragma unroll
          for (int mi = 0; mi < 4; ++mi)
            cacc[mi][nj] = __builtin_amdgcn_mfma_f32_16x16x32_bf16(af[mi], bfr, cacc[mi][nj], 0, 0, 0);
        }
      }
#pragma unroll
      for (int mi = 0; mi < 4; ++mi)
#pragma unroll
        for (int nj = 0; nj < 4; ++nj) {
          f32x4 c = cacc[mi][nj];
#pragma unroll
          for (int r = 0; r < 4; ++r) {
            sum_[mi][r] += c[r];
            sq_[mi][r] += c[r] * c[r];
          }
        }
    }
    __syncthreads();
  }
  // butterfly over the 16-lane col group (lane bits 0..3): total over all 768 d
#pragma unroll
  for (int off = 1; off < 16; off <<= 1)
#pragma unroll
    for (int mi = 0; mi < 4; ++mi)
#pragma unroll
      for (int r = 0; r < 4; ++r) {
        sum_[mi][r] += __shfl_xor(sum_[mi][r], off);
        sq_[mi][r] += __shfl_xor(sq_[mi][r], off);
      }
  if (lr == 0) {
#pragma unroll
    for (int mi = 0; mi < 4; ++mi)
#pragma unroll
      for (int r = 0; r < 4; ++r) {
        int n = w * 64 + mi * 16 + (l >> 4) * 4 + r;
        float mu = sum_[mi][r] * (1.f / 768.f);
        float var = sq_[mi][r] * (1.f / 768.f) - mu * mu;
        mean_s[n] = mu;
        rstd_s[n] = rsqrtf(var + EPS_);
      }
  }

  // ======== PASS 2: conv + LN + PV ========
  // prologue: stage Wcs for chunk 0 (also covers mean_s visibility via the barrier)
#pragma unroll
  for (int it = 0; it < 4; ++it) {
    int idx = it * 256 + t;
    int dd = idx >> 3, seg = (idx & 7) * 8;
    bf16x8 v = *(const bf16x8*)&Wcb[((size_t)g * D_ + dd) * R_ + seg];
    *(bf16x8*)&Wcs[dd * LV1 + seg] = v;
  }
  __syncthreads();

  for (int ci = 0; ci < 6; ++ci) {
    int d0 = ci * 128;
    // ---- conv: wave w owns n-rows [w*64, w*64+64) x all 128 d ----
    f32x4 cacc[4][8];
#pragma unroll
    for (int mi = 0; mi < 4; ++mi)
#pragma unroll
      for (int ni = 0; ni < 8; ++ni) cacc[mi][ni] = (f32x4)0.f;
#pragma unroll
    for (int k0 = 0; k0 < 64; k0 += 32) {
      bf16x8 af[4];
#pragma unroll
      for (int mi = 0; mi < 4; ++mi)
        af[mi] = *(const bf16x8*)&V1s[(w * 64 + mi * 16 + lr) * LV1 + k0 + lk];
#pragma unroll
      for (int ni = 0; ni < 8; ++ni) {
        bf16x8 bfr = *(const bf16x8*)&Wcs[(ni * 16 + lr) * LV1 + k0 + lk];
#pragma unroll
        for (int mi = 0; mi < 4; ++mi)
          cacc[mi][ni] = __builtin_amdgcn_mfma_f32_16x16x32_bf16(af[mi], bfr, cacc[mi][ni], 0, 0, 0);
      }
    }
    // ---- LN epilogue -> Ls[d][n] bf16 ----
    float mn[4][4], rs[4][4];
#pragma unroll
    for (int mi = 0; mi < 4; ++mi)
#pragma unroll
      for (int r = 0; r < 4; ++r) {
        int nrow = w * 64 + mi * 16 + (l >> 4) * 4 + r;
        mn[mi][r] = mean_s[nrow];
        rs[mi][r] = rstd_s[nrow];
      }
    float gc[8], bc[8];
#pragma unroll
    for (int ni = 0; ni < 8; ++ni) {
      gc[ni] = gv2[d0 + ni * 16 + lr];
      bc[ni] = bv2[d0 + ni * 16 + lr];
    }
#pragma unroll
    for (int mi = 0; mi < 4; ++mi)
#pragma unroll
      for (int ni = 0; ni < 8; ++ni) {
        f32x4 c = cacc[mi][ni];
        short4v o = {f2b((c[0] - mn[mi][0]) * rs[mi][0] * gc[ni] + bc[ni]),
                     f2b((c[1] - mn[mi][1]) * rs[mi][1] * gc[ni] + bc[ni]),
                     f2b((c[2] - mn[mi][2]) * rs[mi][2] * gc[ni] + bc[ni]),
                     f2b((c[3] - mn[mi][3]) * rs[mi][3] * gc[ni] + bc[ni])};
        *(short4v*)&Ls[(ni * 16 + lr) * LLS + w * 64 + mi * 16 + (l >> 4) * 4] = o;
      }
    __syncthreads();  // Ls complete; Wcs free

    // ---- PV: wave w owns d-cols [w*32, w*32+32); A rows = head ci (rows 8..15 discarded) ----
    f32x4 acc2[2];
    acc2[0] = (f32x4)0.f; acc2[1] = (f32x4)0.f;
#pragma unroll
    for (int k0 = 0; k0 < 256; k0 += 32) {
      bf16x8 paf = *(const bf16x8*)&As2[(ci * 8 + lr) * LLS + k0 + lk];
#pragma unroll
      for (int nf = 0; nf < 2; ++nf) {
        bf16x8 pbf = *(const bf16x8*)&Ls[(w * 32 + nf * 16 + lr) * LLS + k0 + lk];
        acc2[nf] = __builtin_amdgcn_mfma_f32_16x16x32_bf16(paf, pbf, acc2[nf], 0, 0, 0);
      }
    }
    // stage next chunk's Wcs (overlaps PV epilogue; Wcs unused until after barrier)
    if (ci < 5) {
#pragma unroll
      for (int it = 0; it < 4; ++it) {
        int idx = it * 256 + t;
        int dd = idx >> 3, seg = (idx & 7) * 8;
        bf16x8 v = *(const bf16x8*)&Wcb[((size_t)g * D_ + d0 + 128 + dd) * R_ + seg];
        *(bf16x8*)&Wcs[dd * LV1 + seg] = v;
      }
    }
    // write output rows rr=0..7 (lanes 0..31)
    if (l < 32) {
#pragma unroll
      for (int nf = 0; nf < 2; ++nf)
#pragma unroll
        for (int r = 0; r < 4; ++r) {
          int rr = (l >> 4) * 4 + r;
          int dcol = d0 + w * 32 + nf * 16 + lr;
          aoutb[((size_t)(b * NQ_ + rr * G_ + g)) * D_ + dcol] = f2b(acc2[nf][r]);
        }
    }
    __syncthreads();  // Wcs ready, Ls free
  }
}

// ---------------- launch ----------------
extern "C" void kernel_launch(void* const* d_in, const int* in_sizes, int n_in,
                              void* d_out, int out_size, void* d_ws, size_t ws_size,
                              hipStream_t stream) {
  const float* x       = (const float*)d_in[0];
  const float* context = (const float*)d_in[1];
  const float* Wq  = (const float*)d_in[2];
  const float* gq  = (const float*)d_in[3];
  const float* bq  = (const float*)d_in[4];
  const float* Wk  = (const float*)d_in[5];
  const float* gk  = (const float*)d_in[6];
  const float* bk  = (const float*)d_in[7];
  const float* Wv1 = (const float*)d_in[8];
  const float* gv1 = (const float*)d_in[9];
  const float* bv1 = (const float*)d_in[10];
  const float* Wc  = (const float*)d_in[11];
  const float* gv2 = (const float*)d_in[12];
  const float* bv2 = (const float*)d_in[13];
  const float* Wout = (const float*)d_in[14];
  float* out = (float*)d_out;

  char* p = (char*)d_ws;
  float* tmp   = (float*)p; p += (size_t)4194304 * 4;   // 16.8MB gemm out (reused)
  float* q     = (float*)p; p += (size_t)1572864 * 4;
  float* kT    = (float*)p; p += (size_t)786432 * 4;
  float* attn  = (float*)p; p += (size_t)3145728 * 4;
  short* xb    = (short*)p; p += (size_t)1572864 * 2;
  short* cb    = (short*)p; p += (size_t)786432 * 2;
  short* WqT   = (short*)p; p += (size_t)589824 * 2;
  short* WkT   = (short*)p; p += (size_t)589824 * 2;
  short* Wv1T  = (short*)p; p += (size_t)3145728 * 2;
  short* WoutT = (short*)p; p += (size_t)589824 * 2;
  short* Wcb   = (short*)p; p += (size_t)3145728 * 2;
  short* v1b   = (short*)p; p += (size_t)4194304 * 2;
  short* aoutb = (short*)p; p += (size_t)1572864 * 2;

  dim3 blk(256);
  // casts / transposes
  cast_kernel<<<1536, blk, 0, stream>>>(x, xb, 1572864);
  cast_kernel<<<768, blk, 0, stream>>>(context, cb, 786432);
  cast_kernel<<<3072, blk, 0, stream>>>(Wc, Wcb, 3145728);
  tcast_kernel<<<dim3(24, 24), blk, 0, stream>>>(Wq, WqT, 768, 768);
  tcast_kernel<<<dim3(24, 24), blk, 0, stream>>>(Wk, WkT, 768, 768);
  tcast_kernel<<<dim3(128, 24), blk, 0, stream>>>(Wv1, Wv1T, 768, 4096);
  tcast_kernel<<<dim3(24, 24), blk, 0, stream>>>(Wout, WoutT, 768, 768);
  // q = LN(x @ Wq) * scale   (fp32 q for fp32 attn)
  gemm_bf16_kernel<<<dim3(6, 16), blk, 0, stream>>>(xb, WqT, tmp, 2048, 768, 768);
  ln_kernel<<<2048, blk, 0, stream>>>(tmp, q, gq, bq, 768, SCALE_);
  // kT = LN(ctx @ Wk) * scale, transposed
  gemm_bf16_kernel<<<dim3(6, 8), blk, 0, stream>>>(cb, WkT, tmp, 1024, 768, 768);
  ln_k_kernel<<<1024, blk, 0, stream>>>(tmp, kT, gk, bk);
  // v1 = LN(ctx @ Wv1) -> bf16
  gemm_bf16_kernel<<<dim3(32, 8), blk, 0, stream>>>(cb, Wv1T, tmp, 1024, 4096, 768);
  ln_v1_kernel<<<1024, blk, 0, stream>>>(tmp, v1b, gv1, bv1);
  // attention (fp32)
  attn_kernel<<<dim3(64, 6, 4), blk, 0, stream>>>(q, kT, attn);
  // fused conv+LN+PV (MFMA, two-pass: stats then values)
  pv_mfma_kernel<<<256, blk, 0, stream>>>(v1b, Wcb, attn, gv2, bv2, aoutb);
  // final projection
  gemm_bf16_kernel<<<dim3(6, 16), blk, 0, stream>>>(aoutb, WoutT, out, 2048, 768, 768);
}

// Round 5
// 211.393 us; speedup vs baseline: 7.0320x; 1.3350x over previous
//
#include <hip/hip_runtime.h>
#include <cstddef>

#define B_ 4
#define NQ_ 512
#define N_ 256
#define D_ 768
#define H_ 6
#define DH_ 128
#define G_ 64
#define R_ 64
#define MID_ 4096
#define EPS_ 1e-5f
#define SCALE_ 0.29730177875068026f  // 128^-0.25

typedef short bf16x8 __attribute__((ext_vector_type(8)));
typedef short short4v __attribute__((ext_vector_type(4)));
typedef float f32x4 __attribute__((ext_vector_type(4)));

__device__ __forceinline__ float b2f(short s) {
  union { float f; unsigned u; } c; c.u = ((unsigned)(unsigned short)s) << 16; return c.f;
}
__device__ __forceinline__ short f2b(float f) {
  union { float f; unsigned u; } c; c.f = f;
  unsigned r = c.u + 0x7FFFu + ((c.u >> 16) & 1u);
  return (short)(r >> 16);
}

#define AS1(p) ((const __attribute__((address_space(1))) unsigned int*)(p))
#define AS3(p) ((__attribute__((address_space(3))) unsigned int*)(p))

// ---------------- merged cast fp32->bf16: x | context | Wc ----------------
__global__ __launch_bounds__(256) void cast3_kernel(
    const float* __restrict__ x, short* __restrict__ xb,
    const float* __restrict__ ctx, short* __restrict__ cb,
    const float* __restrict__ Wc, short* __restrict__ Wcb) {
  int bid = blockIdx.x;
  const float* src; short* dst; int i;
  if (bid < 1536)      { src = x;   dst = xb;  i = (bid * 256 + threadIdx.x) * 4; }
  else if (bid < 2304) { src = ctx; dst = cb;  i = ((bid - 1536) * 256 + threadIdx.x) * 4; }
  else                 { src = Wc;  dst = Wcb; i = ((bid - 2304) * 256 + threadIdx.x) * 4; }
  float4 v = *(const float4*)&src[i];
  short4v o = {f2b(v.x), f2b(v.y), f2b(v.z), f2b(v.w)};
  *(short4v*)&dst[i] = o;
}

// ---------------- merged transpose+cast: Wq | Wk | Wout | Wv1 ----------------
__device__ __forceinline__ void tcast_tile(const float* __restrict__ src,
                                           short* __restrict__ dst, int R, int C,
                                           int r0, int c0, float* tile /*32x33*/) {
  int t = threadIdx.x, tc = t & 31, tr = t >> 5;
#pragma unroll
  for (int i = 0; i < 4; ++i)
    tile[(tr + i * 8) * 33 + tc] = src[(size_t)(r0 + tr + i * 8) * C + c0 + tc];
  __syncthreads();
#pragma unroll
  for (int i = 0; i < 4; ++i)
    dst[(size_t)(c0 + tr + i * 8) * R + r0 + tc] = f2b(tile[tc * 33 + tr + i * 8]);
}

__global__ __launch_bounds__(256) void tcast4_kernel(
    const float* __restrict__ Wq, short* __restrict__ WqT,
    const float* __restrict__ Wk, short* __restrict__ WkT,
    const float* __restrict__ Wout, short* __restrict__ WoutT,
    const float* __restrict__ Wv1, short* __restrict__ Wv1T) {
  __shared__ float tile[32 * 33];
  int bid = blockIdx.x;
  if (bid < 576)       tcast_tile(Wq, WqT, 768, 768, (bid / 24) * 32, (bid % 24) * 32, tile);
  else if (bid < 1152) { int o = bid - 576;  tcast_tile(Wk, WkT, 768, 768, (o / 24) * 32, (o % 24) * 32, tile); }
  else if (bid < 1728) { int o = bid - 1152; tcast_tile(Wout, WoutT, 768, 768, (o / 24) * 32, (o % 24) * 32, tile); }
  else                 { int o = bid - 1728; tcast_tile(Wv1, Wv1T, 768, 4096, (o / 128) * 32, (o % 128) * 32, tile); }
}

// ---------------- 128x64 MFMA GEMM tile: C = A(MxK) @ BT(NxK), K mult of 32 ----------------
__device__ __forceinline__ void gemm64_tile(
    const short* __restrict__ A, const short* __restrict__ BT,
    float* __restrict__ C, int N, int K, int m0, int n0,
    short* As /*128*32*/, short* Bs /*64*32*/) {
  int t = threadIdx.x, w = t >> 6, l = t & 63;
  int lr = l & 15, hi = l >> 4, lk = hi * 8;
  int wr = (w >> 1) * 64, wc = (w & 1) * 32;
  f32x4 acc[4][2];
#pragma unroll
  for (int i = 0; i < 4; ++i)
#pragma unroll
    for (int j = 0; j < 2; ++j) acc[i][j] = (f32x4)0.f;
  const short* Ap = A + (size_t)(m0 + (t >> 2)) * K + (t & 3) * 8;
  const short* Bp = BT + (size_t)(n0 + (t >> 2)) * K + (t & 3) * 8;
  for (int k0 = 0; k0 < K; k0 += 32) {
    __builtin_amdgcn_global_load_lds(AS1(Ap + k0), AS3(&As[w * 512]), 16, 0, 0);
    __builtin_amdgcn_global_load_lds(AS1(Ap + (size_t)64 * K + k0), AS3(&As[2048 + w * 512]), 16, 0, 0);
    __builtin_amdgcn_global_load_lds(AS1(Bp + k0), AS3(&Bs[w * 512]), 16, 0, 0);
    __syncthreads();
    bf16x8 af[4], bfr[2];
#pragma unroll
    for (int mi = 0; mi < 4; ++mi) af[mi] = *(const bf16x8*)&As[(wr + mi * 16 + lr) * 32 + lk];
#pragma unroll
    for (int ni = 0; ni < 2; ++ni) bfr[ni] = *(const bf16x8*)&Bs[(wc + ni * 16 + lr) * 32 + lk];
#pragma unroll
    for (int mi = 0; mi < 4; ++mi)
#pragma unroll
      for (int ni = 0; ni < 2; ++ni)
        acc[mi][ni] = __builtin_amdgcn_mfma_f32_16x16x32_bf16(af[mi], bfr[ni], acc[mi][ni], 0, 0, 0);
    __syncthreads();
  }
#pragma unroll
  for (int mi = 0; mi < 4; ++mi)
#pragma unroll
    for (int ni = 0; ni < 2; ++ni)
#pragma unroll
      for (int r = 0; r < 4; ++r)
        C[(size_t)(m0 + wr + mi * 16 + hi * 4 + r) * N + n0 + wc + ni * 16 + lr] = acc[mi][ni][r];
}

// merged projections: q (192 blocks), k (96), v1 (512) -> 800 blocks
__global__ __launch_bounds__(256, 2) void proj_gemm_kernel(
    const short* __restrict__ xb, const short* __restrict__ WqT, float* __restrict__ tq,
    const short* __restrict__ cb, const short* __restrict__ WkT, float* __restrict__ tk,
    const short* __restrict__ Wv1T, float* __restrict__ tv) {
  __shared__ __align__(16) short As[128 * 32];
  __shared__ __align__(16) short Bs[64 * 32];
  int bid = blockIdx.x;
  if (bid < 192)      gemm64_tile(xb, WqT, tq, 768, 768, (bid / 12) * 128, (bid % 12) * 64, As, Bs);
  else if (bid < 288) { int o = bid - 192; gemm64_tile(cb, WkT, tk, 768, 768, (o / 12) * 128, (o % 12) * 64, As, Bs); }
  else                { int o = bid - 288; gemm64_tile(cb, Wv1T, tv, 4096, 768, (o / 64) * 128, (o % 64) * 64, As, Bs); }
}

__global__ __launch_bounds__(256, 2) void out_gemm_kernel(
    const short* __restrict__ aoutb, const short* __restrict__ WoutT, float* __restrict__ C) {
  __shared__ __align__(16) short As[128 * 32];
  __shared__ __align__(16) short Bs[64 * 32];
  int bid = blockIdx.x;
  gemm64_tile(aoutb, WoutT, C, 768, 768, (bid / 12) * 128, (bid % 12) * 64, As, Bs);
}

// ---------------- merged LayerNorm: q -> qb bf16 | k -> kb[b,h,j,d] bf16 | v1 -> v1b ----------------
__global__ __launch_bounds__(256) void ln_all_kernel(
    const float* __restrict__ tq, const float* __restrict__ tk, const float* __restrict__ tv,
    const float* __restrict__ gq, const float* __restrict__ bq,
    const float* __restrict__ gk, const float* __restrict__ bk,
    const float* __restrict__ gv1, const float* __restrict__ bv1,
    short* __restrict__ qb, short* __restrict__ kb, short* __restrict__ v1b) {
  __shared__ float reds[4], redq[4];
  int row = blockIdx.x, t = threadIdx.x;
  const float* src; const float* gamma; const float* beta; int C; float scale;
  if (row < 2048)      { src = tq + (size_t)row * 768; gamma = gq; beta = bq; C = 768; scale = SCALE_; }
  else if (row < 3072) { src = tk + (size_t)(row - 2048) * 768; gamma = gk; beta = bk; C = 768; scale = SCALE_; }
  else                 { src = tv + (size_t)(row - 3072) * 4096; gamma = gv1; beta = bv1; C = 4096; scale = 1.f; }
  float s = 0.f, q2 = 0.f;
  for (int c = t; c < C; c += 256) { float v = src[c]; s += v; q2 += v * v; }
#pragma unroll
  for (int off = 32; off; off >>= 1) { s += __shfl_down(s, off); q2 += __shfl_down(q2, off); }
  int w = t >> 6;
  if ((t & 63) == 0) { reds[w] = s; redq[w] = q2; }
  __syncthreads();
  s = reds[0] + reds[1] + reds[2] + reds[3];
  q2 = redq[0] + redq[1] + redq[2] + redq[3];
  float mu = s / C, var = q2 / C - mu * mu;
  float rstd = rsqrtf(var + EPS_);
  if (row < 2048) {
    for (int c = t; c < C; c += 256)
      qb[(size_t)row * 768 + c] = f2b(((src[c] - mu) * rstd * gamma[c] + beta[c]) * scale);
  } else if (row < 3072) {
    int rr = row - 2048, b = rr >> 8, j = rr & 255;
    for (int c = t; c < C; c += 256) {
      short val = f2b(((src[c] - mu) * rstd * gamma[c] + beta[c]) * scale);
      kb[((size_t)((b * H_ + (c >> 7)) * N_ + j)) * DH_ + (c & 127)] = val;
    }
  } else {
    int rr = row - 3072;
    for (int c = t; c < C; c += 256)
      v1b[(size_t)rr * MID_ + c] = f2b((src[c] - mu) * rstd * gamma[c] + beta[c]);
  }
}

// ---------------- attention QK^T + softmax via MFMA, no LDS ----------------
// grid (8 i-tiles, H, B), 256 thr = 4 waves; wave owns 16 q-rows x 256 j.
__global__ __launch_bounds__(256, 2) void attn_mfma_kernel(
    const short* __restrict__ qb, const short* __restrict__ kb, short* __restrict__ Ps) {
  int b = blockIdx.z, h = blockIdx.y, i0 = blockIdx.x * 64;
  int t = threadIdx.x, w = t >> 6, l = t & 63;
  int lr = l & 15, hi = l >> 4;
  bf16x8 af[4];
  const short* qp = qb + ((size_t)(b * NQ_ + i0 + w * 16 + lr)) * D_ + h * DH_ + hi * 8;
#pragma unroll
  for (int kk = 0; kk < 4; ++kk) af[kk] = *(const bf16x8*)(qp + kk * 32);
  f32x4 acc[16];
#pragma unroll
  for (int jf = 0; jf < 16; ++jf) acc[jf] = (f32x4)0.f;
  const short* kp = kb + ((size_t)((b * H_ + h) * N_ + lr)) * DH_ + hi * 8;
#pragma unroll
  for (int kk = 0; kk < 4; ++kk)
#pragma unroll
    for (int jf = 0; jf < 16; ++jf) {
      bf16x8 bfr = *(const bf16x8*)(kp + jf * 16 * DH_ + kk * 32);
      acc[jf] = __builtin_amdgcn_mfma_f32_16x16x32_bf16(af[kk], bfr, acc[jf], 0, 0, 0);
    }
  // softmax across 256 cols: per lane 4 rows x 16 col-samples; 16-lane butterfly completes rows
  float mx[4], sum[4];
#pragma unroll
  for (int r = 0; r < 4; ++r) {
    mx[r] = acc[0][r];
#pragma unroll
    for (int jf = 1; jf < 16; ++jf) mx[r] = fmaxf(mx[r], acc[jf][r]);
  }
#pragma unroll
  for (int off = 1; off < 16; off <<= 1)
#pragma unroll
    for (int r = 0; r < 4; ++r) mx[r] = fmaxf(mx[r], __shfl_xor(mx[r], off));
#pragma unroll
  for (int r = 0; r < 4; ++r) sum[r] = 0.f;
#pragma unroll
  for (int jf = 0; jf < 16; ++jf)
#pragma unroll
    for (int r = 0; r < 4; ++r) {
      float p = __expf(acc[jf][r] - mx[r]);
      acc[jf][r] = p; sum[r] += p;
    }
#pragma unroll
  for (int off = 1; off < 16; off <<= 1)
#pragma unroll
    for (int r = 0; r < 4; ++r) sum[r] += __shfl_xor(sum[r], off);
  float inv[4];
#pragma unroll
  for (int r = 0; r < 4; ++r) inv[r] = 1.f / sum[r];
  short* pp = Ps + ((size_t)((b * H_ + h) * NQ_ + i0 + w * 16 + hi * 4)) * N_ + lr;
#pragma unroll
  for (int jf = 0; jf < 16; ++jf)
#pragma unroll
    for (int r = 0; r < 4; ++r)
      pp[(size_t)r * N_ + jf * 16] = f2b(acc[jf][r] * inv[r]);
}

// ---------------- fused conv+LN+PV via MFMA: block per (b,g), 512 thr = 8 waves ----------------
// XOR-swizzled Ls/As2 (stride 256 shorts): phys_byte = ((b>>4 ^ ((row&7)<<2))<<4) | (b&15).
// PASS1 conv -> per-row sum/sumsq (butterfly over 16-lane col group) -> mean/rstd.
// PASS2 conv -> LN -> Ls[d][n] bf16 -> PV (P @ L) -> out bf16.
__global__ __launch_bounds__(512, 2) void pv_mfma_kernel(
    const short* __restrict__ v1b, const short* __restrict__ Wcb,
    const short* __restrict__ Ps, const float* __restrict__ gv2,
    const float* __restrict__ bv2, short* __restrict__ aoutb) {
  __shared__ __align__(16) short V1s[256 * 72];   // 36.9KB [n][r], 9-slot stride (conflict-free)
  __shared__ __align__(16) short Wcs[128 * 72];   // 18.4KB [d][r]
  __shared__ __align__(16) short Ls[128 * 256];   // 64KB   [d][n] swizzled
  __shared__ __align__(16) short As2[56 * 256];   // 28.7KB [h*8+rr][n] swizzled
  __shared__ float mean_s[256], rstd_s[256];
  int bg = blockIdx.x, b = bg >> 6, g = bg & 63;
  int t = threadIdx.x, w = t >> 6, l = t & 63;
  int lr = l & 15, hi = l >> 4, lk = hi * 8;

  // stage V1 slice [256][64]
#pragma unroll
  for (int it = 0; it < 4; ++it) {
    int idx = it * 512 + t;
    int n = idx >> 3, seg = (idx & 7) * 8;
    *(bf16x8*)&V1s[n * 72 + seg] =
        *(const bf16x8*)&v1b[((size_t)(b * N_ + n)) * MID_ + g * R_ + seg];
  }
  // stage P rows (48) bf16, swizzled
#pragma unroll
  for (int it = 0; it < 6; ++it) {
    int e = it * 512 + t;
    int i = e >> 6, q4 = e & 63;
    short4v v = *(const short4v*)&Ps[((size_t)((b * H_ + (i >> 3)) * NQ_ + (i & 7) * G_ + g)) * N_ + q4 * 4];
    int phys = (((q4 >> 1) ^ ((i & 7) << 2)) << 4) | ((q4 & 1) << 3);
    *(short4v*)((char*)&As2[i * 256] + phys) = v;
  }
  // zero pad rows 48..55
  {
    short4v z = {0, 0, 0, 0};
    *(short4v*)&As2[48 * 256 + t * 4] = z;
  }

  // ======== PASS 1: conv-only, stats ========
  float sum_[2][4], sq_[2][4];
#pragma unroll
  for (int mi = 0; mi < 2; ++mi)
#pragma unroll
    for (int r = 0; r < 4; ++r) { sum_[mi][r] = 0.f; sq_[mi][r] = 0.f; }

  for (int ci = 0; ci < 6; ++ci) {
#pragma unroll
    for (int it = 0; it < 2; ++it) {
      int e = it * 512 + t;
      int dd = e >> 3, seg = (e & 7) * 8;
      *(bf16x8*)&Wcs[dd * 72 + seg] =
          *(const bf16x8*)&Wcb[((size_t)(g * D_ + ci * 128 + dd)) * R_ + seg];
    }
    __syncthreads();
#pragma unroll
    for (int nb = 0; nb < 2; ++nb) {
      f32x4 cacc[2][4];
#pragma unroll
      for (int mi = 0; mi < 2; ++mi)
#pragma unroll
        for (int nj = 0; nj < 4; ++nj) cacc[mi][nj] = (f32x4)0.f;
#pragma unroll
      for (int k0 = 0; k0 < 64; k0 += 32) {
        bf16x8 a0 = *(const bf16x8*)&V1s[(w * 32 + lr) * 72 + k0 + lk];
        bf16x8 a1 = *(const bf16x8*)&V1s[(w * 32 + 16 + lr) * 72 + k0 + lk];
#pragma unroll
        for (int nj = 0; nj < 4; ++nj) {
          bf16x8 bfr = *(const bf16x8*)&Wcs[((nb * 4 + nj) * 16 + lr) * 72 + k0 + lk];
          cacc[0][nj] = __builtin_amdgcn_mfma_f32_16x16x32_bf16(a0, bfr, cacc[0][nj], 0, 0, 0);
          cacc[1][nj] = __builtin_amdgcn_mfma_f32_16x16x32_bf16(a1, bfr, cacc[1][nj], 0, 0, 0);
        }
      }
#pragma unroll
      for (int mi = 0; mi < 2; ++mi)
#pragma unroll
        for (int nj = 0; nj < 4; ++nj) {
          f32x4 c = cacc[mi][nj];
#pragma unroll
          for (int r = 0; r < 4; ++r) { sum_[mi][r] += c[r]; sq_[mi][r] += c[r] * c[r]; }
        }
    }
    __syncthreads();
  }
#pragma unroll
  for (int off = 1; off < 16; off <<= 1)
#pragma unroll
    for (int mi = 0; mi < 2; ++mi)
#pragma unroll
      for (int r = 0; r < 4; ++r) {
        sum_[mi][r] += __shfl_xor(sum_[mi][r], off);
        sq_[mi][r] += __shfl_xor(sq_[mi][r], off);
      }
  if (lr == 0) {
#pragma unroll
    for (int mi = 0; mi < 2; ++mi)
#pragma unroll
      for (int r = 0; r < 4; ++r) {
        int n = w * 32 + mi * 16 + hi * 4 + r;
        float mu = sum_[mi][r] * (1.f / 768.f);
        float var = sq_[mi][r] * (1.f / 768.f) - mu * mu;
        mean_s[n] = mu;
        rstd_s[n] = rsqrtf(var + EPS_);
      }
  }

  // ======== PASS 2 ========
#pragma unroll
  for (int it = 0; it < 2; ++it) {
    int e = it * 512 + t;
    int dd = e >> 3, seg = (e & 7) * 8;
    *(bf16x8*)&Wcs[dd * 72 + seg] = *(const bf16x8*)&Wcb[((size_t)(g * D_ + dd)) * R_ + seg];
  }
  __syncthreads();

  for (int ci = 0; ci < 6; ++ci) {
    int d0 = ci * 128;
    f32x4 cacc[2][8];
#pragma unroll
    for (int mi = 0; mi < 2; ++mi)
#pragma unroll
      for (int ni = 0; ni < 8; ++ni) cacc[mi][ni] = (f32x4)0.f;
#pragma unroll
    for (int k0 = 0; k0 < 64; k0 += 32) {
      bf16x8 a0 = *(const bf16x8*)&V1s[(w * 32 + lr) * 72 + k0 + lk];
      bf16x8 a1 = *(const bf16x8*)&V1s[(w * 32 + 16 + lr) * 72 + k0 + lk];
#pragma unroll
      for (int ni = 0; ni < 8; ++ni) {
        bf16x8 bfr = *(const bf16x8*)&Wcs[(ni * 16 + lr) * 72 + k0 + lk];
        cacc[0][ni] = __builtin_amdgcn_mfma_f32_16x16x32_bf16(a0, bfr, cacc[0][ni], 0, 0, 0);
        cacc[1][ni] = __builtin_amdgcn_mfma_f32_16x16x32_bf16(a1, bfr, cacc[1][ni], 0, 0, 0);
      }
    }
    // LN epilogue -> swizzled Ls[d][n]
    float mn[2][4], rs[2][4];
#pragma unroll
    for (int mi = 0; mi < 2; ++mi)
#pragma unroll
      for (int r = 0; r < 4; ++r) {
        int nrow = w * 32 + mi * 16 + hi * 4 + r;
        mn[mi][r] = mean_s[nrow];
        rs[mi][r] = rstd_s[nrow];
      }
    float gc[8], bc[8];
#pragma unroll
    for (int ni = 0; ni < 8; ++ni) {
      gc[ni] = gv2[d0 + ni * 16 + lr];
      bc[ni] = bv2[d0 + ni * 16 + lr];
    }
#pragma unroll
    for (int mi = 0; mi < 2; ++mi)
#pragma unroll
      for (int ni = 0; ni < 8; ++ni) {
        f32x4 c = cacc[mi][ni];
        short4v o = {f2b((c[0] - mn[mi][0]) * rs[mi][0] * gc[ni] + bc[ni]),
                     f2b((c[1] - mn[mi][1]) * rs[mi][1] * gc[ni] + bc[ni]),
                     f2b((c[2] - mn[mi][2]) * rs[mi][2] * gc[ni] + bc[ni]),
                     f2b((c[3] - mn[mi][3]) * rs[mi][3] * gc[ni] + bc[ni])};
        int row = ni * 16 + lr;
        int bcol = w * 64 + mi * 32 + hi * 8;
        int phys = (((bcol >> 4) ^ ((lr & 7) << 2)) << 4) | (bcol & 15);
        *(short4v*)((char*)&Ls[row * 256] + phys) = o;
      }
    __syncthreads();  // Ls complete; Wcs free

    // PV: wave w owns d-cols [w*16, w*16+16); A rows = head ci (rows 8..15 discarded)
    f32x4 acc2 = (f32x4)0.f;
#pragma unroll
    for (int k0 = 0; k0 < 256; k0 += 32) {
      int physoff = ((((k0 >> 3) + hi) ^ ((lr & 7) << 2)) << 4);
      bf16x8 pa = *(const bf16x8*)((char*)&As2[(ci * 8 + lr) * 256] + physoff);
      bf16x8 pb = *(const bf16x8*)((char*)&Ls[(w * 16 + lr) * 256] + physoff);
      acc2 = __builtin_amdgcn_mfma_f32_16x16x32_bf16(pa, pb, acc2, 0, 0, 0);
    }
    // stage next chunk's Wcs (safe: all waves past conv reads of this chunk)
    if (ci < 5) {
#pragma unroll
      for (int it = 0; it < 2; ++it) {
        int e = it * 512 + t;
        int dd = e >> 3, seg = (e & 7) * 8;
        *(bf16x8*)&Wcs[dd * 72 + seg] =
            *(const bf16x8*)&Wcb[((size_t)(g * D_ + d0 + 128 + dd)) * R_ + seg];
      }
    }
    if (hi < 2) {
      int dcol = d0 + w * 16 + lr;
#pragma unroll
      for (int r = 0; r < 4; ++r) {
        int rr = hi * 4 + r;
        aoutb[((size_t)(b * NQ_ + rr * G_ + g)) * D_ + dcol] = f2b(acc2[r]);
      }
    }
    __syncthreads();  // Wcs ready, Ls free
  }
}

// ---------------- launch ----------------
extern "C" void kernel_launch(void* const* d_in, const int* in_sizes, int n_in,
                              void* d_out, int out_size, void* d_ws, size_t ws_size,
                              hipStream_t stream) {
  const float* x       = (const float*)d_in[0];
  const float* context = (const float*)d_in[1];
  const float* Wq  = (const float*)d_in[2];
  const float* gq  = (const float*)d_in[3];
  const float* bq  = (const float*)d_in[4];
  const float* Wk  = (const float*)d_in[5];
  const float* gk  = (const float*)d_in[6];
  const float* bk  = (const float*)d_in[7];
  const float* Wv1 = (const float*)d_in[8];
  const float* gv1 = (const float*)d_in[9];
  const float* bv1 = (const float*)d_in[10];
  const float* Wc  = (const float*)d_in[11];
  const float* gv2 = (const float*)d_in[12];
  const float* bv2 = (const float*)d_in[13];
  const float* Wout = (const float*)d_in[14];
  float* out = (float*)d_out;

  char* p = (char*)d_ws;
  float* tq   = (float*)p; p += (size_t)1572864 * 4;
  float* tk   = (float*)p; p += (size_t)786432 * 4;
  float* tv   = (float*)p; p += (size_t)4194304 * 4;
  short* xb   = (short*)p; p += (size_t)1572864 * 2;
  short* cb   = (short*)p; p += (size_t)786432 * 2;
  short* WqT  = (short*)p; p += (size_t)589824 * 2;
  short* WkT  = (short*)p; p += (size_t)589824 * 2;
  short* Wv1T = (short*)p; p += (size_t)3145728 * 2;
  short* WoutT= (short*)p; p += (size_t)589824 * 2;
  short* Wcb  = (short*)p; p += (size_t)3145728 * 2;
  short* qb   = (short*)p; p += (size_t)1572864 * 2;
  short* kb   = (short*)p; p += (size_t)786432 * 2;
  short* v1b  = (short*)p; p += (size_t)4194304 * 2;
  short* Ps   = (short*)p; p += (size_t)3145728 * 2;
  short* aoutb= (short*)p; p += (size_t)1572864 * 2;

  dim3 blk(256);
  cast3_kernel<<<5376, blk, 0, stream>>>(x, xb, context, cb, Wc, Wcb);
  tcast4_kernel<<<4800, blk, 0, stream>>>(Wq, WqT, Wk, WkT, Wout, WoutT, Wv1, Wv1T);
  proj_gemm_kernel<<<800, blk, 0, stream>>>(xb, WqT, tq, cb, WkT, tk, Wv1T, tv);
  ln_all_kernel<<<4096, blk, 0, stream>>>(tq, tk, tv, gq, bq, gk, bk, gv1, bv1, qb, kb, v1b);
  attn_mfma_kernel<<<dim3(8, H_, B_), blk, 0, stream>>>(qb, kb, Ps);
  pv_mfma_kernel<<<B_ * G_, dim3(512), 0, stream>>>(v1b, Wcb, Ps, gv2, bv2, aoutb);
  out_gemm_kernel<<<192, blk, 0, stream>>>(aoutb, WoutT, out);
}